// Round 6
// baseline (604.886 us; speedup 1.0000x reference)
//
#include <hip/hip_runtime.h>
#include <stdint.h>
#include <stddef.h>

// ---------------- problem constants ----------------
constexpr int BB = 4, SS = 2048, DD = 512, HH = 8, LL = 4;
constexpr int NTOK = BB * SS;          // 8192 tokens
constexpr float BN_EPS = 1e-3f;

using bh = __bf16;
typedef __bf16 bf16x8 __attribute__((ext_vector_type(8)));
typedef float  f32x4  __attribute__((ext_vector_type(4)));

#define DEV __device__ __forceinline__
#define WAITVM(n) asm volatile("s_waitcnt vmcnt(" #n ")" ::: "memory")
#define WAITLGKM0 asm volatile("s_waitcnt lgkmcnt(0)" ::: "memory")
#define MEMBAR    asm volatile("" ::: "memory")

DEV void gload_lds16(const void* g, void* l) {
    __builtin_amdgcn_global_load_lds(
        (const __attribute__((address_space(1))) void*)g,
        (__attribute__((address_space(3))) void*)l, 16, 0, 0);
}

// ---------------- weight prep (all 6 matrices, one dispatch) ----------------
// f32 [512][512] -> bf16 transposed. z = m*4 + l, m in {wq,wk,wv,wo,d1,d2}.
__global__ void wprep_all(const float* __restrict__ wq, const float* __restrict__ wk,
                          const float* __restrict__ wv, const float* __restrict__ wo,
                          const float* __restrict__ d1, const float* __restrict__ d2,
                          bh* __restrict__ wcat, bh* __restrict__ wot,
                          bh* __restrict__ w1t, bh* __restrict__ w2t) {
    __shared__ float t[32][33];
    const int z = blockIdx.z;              // 0..23
    const int m = z >> 2, l = z & 3;
    constexpr int QOS = 3 * DD * DD;
    const float* src;
    bh* dst;
    switch (m) {
        case 0:  src = wq; dst = wcat + (size_t)l * QOS;               break;
        case 1:  src = wk; dst = wcat + (size_t)l * QOS + DD * DD;     break;
        case 2:  src = wv; dst = wcat + (size_t)l * QOS + 2 * DD * DD; break;
        case 3:  src = wo; dst = wot + (size_t)l * DD * DD;            break;
        case 4:  src = d1; dst = w1t + (size_t)l * DD * DD;            break;
        default: src = d2; dst = w2t + (size_t)l * DD * DD;            break;
    }
    src += (size_t)l * DD * DD;
    const int r0 = blockIdx.y * 32, c0 = blockIdx.x * 32;
    const int tx = threadIdx.x, ty = threadIdx.y;   // 32 x 8
    #pragma unroll
    for (int i = ty; i < 32; i += 8) t[i][tx] = src[(size_t)(r0 + i) * DD + c0 + tx];
    __syncthreads();
    #pragma unroll
    for (int i = ty; i < 32; i += 8) dst[(size_t)(c0 + i) * DD + r0 + tx] = (bh)t[tx][i];
}

// ---------------- mask bias: [B,S] f32 -> 0 / -1e30 ----------------
__global__ void maskprep(const float* __restrict__ mask, float* __restrict__ mb) {
    const int i = ((int)blockIdx.x * 256 + threadIdx.x) * 4;
    const float4 m4 = *(const float4*)(mask + i);
    float4 o;
    o.x = (m4.x == 0.f) ? -1e30f : 0.f;
    o.y = (m4.y == 0.f) ? -1e30f : 0.f;
    o.z = (m4.z == 0.f) ? -1e30f : 0.f;
    o.w = (m4.w == 0.f) ? -1e30f : 0.f;
    *(float4*)(mb + i) = o;
}

// ---------------- embedding + positional -> bf16 ----------------
__global__ void embed_k(const int* __restrict__ seq, const float* __restrict__ emb,
                        const float* __restrict__ pos, bh* __restrict__ xb) {
    const int m = blockIdx.x;                // 0..8191
    const int s = m & (SS - 1);
    const int tok = seq[m];
    const int d = threadIdx.x * 4;           // 128 threads * 4 floats
    const float4 e  = *(const float4*)(emb + (size_t)tok * DD + d);
    const float4 pz = *(const float4*)(pos + (size_t)s * DD + d);
    union { bh h[4]; uint64_t u; } pk;
    pk.h[0] = (bh)(e.x + pz.x); pk.h[1] = (bh)(e.y + pz.y);
    pk.h[2] = (bh)(e.z + pz.z); pk.h[3] = (bh)(e.w + pz.w);
    *(uint64_t*)(xb + (size_t)m * DD + d) = pk.u;
}

// ---------------- EP GEMM: 64x64 tile, A in LDS (3-buf), B direct global->reg ------------
// C[8192,512] = A @ Bt^T; grid 1024, 4 waves (32x32 wave tiles), full-unrolled K loop.
// EP 1: t = resb + acc + bias; s = BN(t); outb = bf16(s); if WF32: Xo = s
// EP 2: outb = bf16(relu(acc + bias))
template <int EP, bool WF32>
__global__ __launch_bounds__(256, 4)
void gemm_ep(const bh* __restrict__ A, const bh* __restrict__ Bt,
             const float* __restrict__ bias, bh* __restrict__ outb,
             const bh* __restrict__ resb, float* __restrict__ Xo,
             const float* __restrict__ gamma, const float* __restrict__ beta,
             const float* __restrict__ mean, const float* __restrict__ var) {
    constexpr int BK = 64, NKT = DD / BK;        // 8 k-tiles
    __shared__ __align__(16) bh As[3][64 * BK];  // 3 x 8 KB

    const int tid = threadIdx.x;
    const int w = tid >> 6, lane = tid & 63;
    const int l15 = lane & 15, l4 = lane >> 4;
    const int i = (int)blockIdx.x;
    const int xcd = i & 7, j = i >> 3;           // j 0..127
    const int bm = xcd * 16 + (j >> 3);          // 0..127
    const int bn = j & 7;                        // 0..7
    const int m0 = bm * 64, n0 = bn * 64;
    const int wr = w >> 1, wc = w & 1;           // wave tile 32x32

    f32x4 acc[2][2] = {};
    const int sr = lane >> 3;
    const int cbx = (lane & 7) ^ sr;

    auto stageA = [&](int buf, int kk) {
        #pragma unroll
        for (int ii = 0; ii < 2; ++ii) {
            const int idx = w * 2 + ii;
            const int r = idx * 8 + sr;
            gload_lds16(A + (size_t)(m0 + r) * DD + kk + 8 * cbx, &As[buf][idx * 512]);
        }
    };

    // B per-lane global base: row n = n0 + wc*32 + nf*16 + l15, k-slice l4*8
    const bh* bg = Bt + (size_t)(n0 + wc * 32 + l15) * DD + l4 * 8;
    bf16x8 bqA[2][2], bqB[2][2];   // [ks][nf], double-generation

    // prologue: regions [A0,B0] | [A1,B1]  (12 vmem ops outstanding)
    stageA(0, 0);
    #pragma unroll
    for (int ks = 0; ks < 2; ++ks)
        #pragma unroll
        for (int nf = 0; nf < 2; ++nf)
            bqA[ks][nf] = *(const bf16x8*)(bg + nf * 16 * DD + ks * 32);
    MEMBAR;
    stageA(1, BK);
    #pragma unroll
    for (int ks = 0; ks < 2; ++ks)
        #pragma unroll
        for (int nf = 0; nf < 2; ++nf)
            bqB[ks][nf] = *(const bf16x8*)(bg + nf * 16 * DD + BK + ks * 32);
    MEMBAR;

    #pragma unroll
    for (int kt = 0; kt < NKT; ++kt) {
        if (kt < NKT - 1) { WAITVM(6); } else { WAITVM(0); }
        __builtin_amdgcn_s_barrier();

        bf16x8 (*bq)[2] = (kt & 1) ? bqB : bqA;
        const char* Ab = (const char*)&As[kt % 3][0];
        #pragma unroll
        for (int ks = 0; ks < 2; ++ks) {
            bf16x8 af[2];
            const int cby = ks * 64 + l4 * 16;
            #pragma unroll
            for (int mf = 0; mf < 2; ++mf) {
                const int row = wr * 32 + mf * 16 + l15;
                af[mf] = *(const bf16x8*)(Ab + row * 128 + (cby ^ ((row & 7) << 4)));
            }
            __builtin_amdgcn_s_setprio(1);
            #pragma unroll
            for (int mf = 0; mf < 2; ++mf)
                #pragma unroll
                for (int nf = 0; nf < 2; ++nf)
                    acc[mf][nf] = __builtin_amdgcn_mfma_f32_16x16x32_bf16(
                        af[mf], bq[ks][nf], acc[mf][nf], 0, 0, 0);
            __builtin_amdgcn_s_setprio(0);
        }

        // bottom: issue next-next tile (A -> LDS, B -> regs of the now-dead generation)
        if (kt + 2 < NKT) {
            stageA((kt + 2) % 3, (kt + 2) * BK);
            bf16x8 (*bqn)[2] = (kt & 1) ? bqB : bqA;   // same parity as kt -> dead now
            #pragma unroll
            for (int ks = 0; ks < 2; ++ks)
                #pragma unroll
                for (int nf = 0; nf < 2; ++nf)
                    bqn[ks][nf] = *(const bf16x8*)(bg + nf * 16 * DD + (kt + 2) * BK + ks * 32);
        }
    }

    // epilogue: m = l4*4 + r rows, n = l15 cols
    #pragma unroll
    for (int nf = 0; nf < 2; ++nf) {
        const int n = n0 + wc * 32 + nf * 16 + l15;
        const float bi = bias[n];
        float g = 0.f, be = 0.f, mu = 0.f, iv = 0.f;
        if constexpr (EP == 1) {
            g = gamma[n]; be = beta[n]; mu = mean[n];
            iv = rsqrtf(var[n] + BN_EPS);
        }
        #pragma unroll
        for (int mf = 0; mf < 2; ++mf) {
            #pragma unroll
            for (int r = 0; r < 4; ++r) {
                const int m = m0 + wr * 32 + mf * 16 + l4 * 4 + r;
                const size_t off = (size_t)m * DD + n;
                const float v = acc[mf][nf][r] + bi;
                if constexpr (EP == 2) {
                    outb[off] = (bh)fmaxf(v, 0.f);
                } else {
                    const float t = (float)resb[off] + v;
                    const float s = (t - mu) * iv * g + be;
                    outb[off] = (bh)s;
                    if constexpr (WF32) Xo[off] = s;
                }
            }
        }
    }
}

// ---------------- fused QKV GEMM: C[8192,1536] = xb @ Wcat^T; V written transposed ---------
__global__ __launch_bounds__(256, 3)
void gemm_qkv(const bh* __restrict__ A, const bh* __restrict__ Bt,
              const float* __restrict__ bq, const float* __restrict__ bk,
              const float* __restrict__ bv,
              bh* __restrict__ qb, bh* __restrict__ kb, bh* __restrict__ vT) {
    constexpr int BM = 128, BN = 64, BK = 64, NKT = DD / BK;
    __shared__ __align__(16) bh As[2][BM * BK];
    __shared__ __align__(16) bh Bs[2][BN * BK];

    const int tid = threadIdx.x;
    const int w = tid >> 6, lane = tid & 63;
    const int l15 = lane & 15, l4 = lane >> 4;
    const int i = (int)blockIdx.x;
    const int xcd = i & 7, j = i >> 3;        // j 0..191
    const int bm = xcd * 8 + (j & 7);         // 0..63
    const int bn = j >> 3;                    // 0..23
    const int m0 = bm * BM, n0 = bn * BN;
    const int wr = w >> 1, wc = w & 1;

    f32x4 acc[4][2] = {};
    const int sr = lane >> 3;
    const int cbx = (lane & 7) ^ sr;

    auto stage = [&](int buf, int kk) {
        #pragma unroll
        for (int ii = 0; ii < 4; ++ii) {
            const int idx = w * 4 + ii;
            const int r = idx * 8 + sr;
            gload_lds16(A + (size_t)(m0 + r) * DD + kk + 8 * cbx, &As[buf][idx * 512]);
        }
        #pragma unroll
        for (int ii = 0; ii < 2; ++ii) {
            const int idx = w * 2 + ii;
            const int r = idx * 8 + sr;
            gload_lds16(Bt + (size_t)(n0 + r) * DD + kk + 8 * cbx, &Bs[buf][idx * 512]);
        }
    };

    stage(0, 0);
    stage(1, BK);

    for (int kt = 0; kt < NKT; ++kt) {
        const int buf = kt & 1;
        if (kt + 1 < NKT) { WAITVM(6); } else { WAITVM(0); }
        __builtin_amdgcn_s_barrier();

        const char* Ab = (const char*)&As[buf][0];
        const char* Bb = (const char*)&Bs[buf][0];
        #pragma unroll
        for (int ks = 0; ks < 2; ++ks) {
            bf16x8 af[4], bfr[2];
            const int cby = ks * 64 + l4 * 16;
            #pragma unroll
            for (int mf = 0; mf < 4; ++mf) {
                const int row = wr * 64 + mf * 16 + l15;
                af[mf] = *(const bf16x8*)(Ab + row * 128 + (cby ^ ((row & 7) << 4)));
            }
            #pragma unroll
            for (int nf = 0; nf < 2; ++nf) {
                const int row = wc * 32 + nf * 16 + l15;
                bfr[nf] = *(const bf16x8*)(Bb + row * 128 + (cby ^ ((row & 7) << 4)));
            }
            #pragma unroll
            for (int mf = 0; mf < 4; ++mf)
                #pragma unroll
                for (int nf = 0; nf < 2; ++nf)
                    acc[mf][nf] = __builtin_amdgcn_mfma_f32_16x16x32_bf16(
                        af[mf], bfr[nf], acc[mf][nf], 0, 0, 0);
        }
        WAITLGKM0;
        __builtin_amdgcn_s_barrier();
        if (kt + 2 < NKT) stage(buf, (kt + 2) * BK);
    }

    const int part = n0 >> 9;                 // uniform per block: 0=Q 1=K 2=V
    #pragma unroll
    for (int nf = 0; nf < 2; ++nf) {
        const int n = n0 + wc * 32 + nf * 16 + l15;
        const int nn = n & 511;
        const float bi = (part == 0 ? bq : part == 1 ? bk : bv)[nn];
        if (part < 2) {
            bh* out = part ? kb : qb;
            #pragma unroll
            for (int mf = 0; mf < 4; ++mf)
                #pragma unroll
                for (int r = 0; r < 4; ++r) {
                    const int m = m0 + wr * 64 + mf * 16 + l4 * 4 + r;
                    out[(size_t)m * DD + nn] = (bh)(acc[mf][nf][r] + bi);
                }
        } else {
            const int hh = nn >> 6, dk = nn & 63;
            #pragma unroll
            for (int mf = 0; mf < 4; ++mf) {
                const int m = m0 + wr * 64 + mf * 16 + l4 * 4;   // r = 0..3 consecutive
                const int bb2 = m >> 11, s = m & (SS - 1);
                union { bh h4[4]; uint64_t u; } pk;
                #pragma unroll
                for (int r = 0; r < 4; ++r)
                    pk.h4[r] = (bh)(acc[mf][nf][r] + bi);
                *(uint64_t*)(vT + ((size_t)((bb2 * HH + hh) * 64) + dk) * SS + s) = pk.u;
            }
        }
    }
}

// ---------------- flash attention v6 ----------------
// grid 1024 (XCD-pinned), 2 waves x 32q (two 16-row sets) = 64 q/block, KVB=32.
// LDS ~21.5KB -> 4 blocks/CU x 2 waves = 8 waves/CU; K/V LDS reads amortized over 2 sets.
// Swapped MFMA, in-reg softmax (log2 domain), defer-max, lrun via ones-MFMA.
__global__ __launch_bounds__(128, 2)
void flash_attn(const bh* __restrict__ Q, const bh* __restrict__ K,
                const bh* __restrict__ VT, const float* __restrict__ mb,
                bh* __restrict__ O) {
    constexpr int KVB = 32, NT = SS / KVB;       // 64 tiles
    constexpr float CSC = 0.18033688f;           // 0.125 * log2(e)
    __shared__ __align__(16) bh Ks[2][KVB * 64]; // 2 x 4 KB [key][dk]
    __shared__ __align__(16) bh Vs[2][64 * KVB]; // 2 x 4 KB [dk][key]
    __shared__ __align__(16) bh Plds[2][2][16 * 40]; // wave x set, row stride 80 B

    const int tid = threadIdx.x;
    const int w = tid >> 6, lane = tid & 63;     // w in {0,1}
    const int l15 = lane & 15, l4 = lane >> 4;

    const int i = (int)blockIdx.x;
    const int xcd = i & 7, j = i >> 3;           // j 0..127
    const int g = xcd * 4 + (j >> 5);            // (b,h) group 0..31
    const int qt = j & 31;
    const int h = g & 7, b = g >> 3;

    const int q0 = qt * 64 + w * 32;

    // Q fragments: set st covers q = q0 + st*16 + l15
    bf16x8 qf[2][2];
    #pragma unroll
    for (int st = 0; st < 2; ++st) {
        const bh* qp = Q + (size_t)(b * SS + q0 + st * 16 + l15) * DD + h * 64 + l4 * 8;
        qf[st][0] = *(const bf16x8*)qp;
        qf[st][1] = *(const bf16x8*)(qp + 32);
    }

    f32x4 ctx[2][4] = {};
    f32x4 accl[2] = {};
    float m2[2] = {-3e38f, -3e38f};

    bf16x8 ones;
    #pragma unroll
    for (int z = 0; z < 8; ++z) ones[z] = (bh)1.0f;

    // staging geometry (2 waves x 2 chunks each): K 32x128B, V 64x64B
    const int ksr = lane >> 3;                   // K row-in-8
    const int kcb = (lane & 7) ^ ksr;            // K src 16B slot (xor row&7)
    const int vrow = lane >> 2;                  // V row-in-16
    const int vcb  = (lane & 3) ^ (vrow & 3);    // V src 16B slot (xor row&3)

    const bh* kg = K + ((size_t)(b * SS) + ksr) * DD + h * 64 + 8 * kcb;
    const bh* vg = VT + ((size_t)((b * HH + h) * 64) + vrow) * SS + 8 * vcb;
    const float* mbb = mb + (size_t)b * SS + l4 * 4;

    auto stage = [&](int buf, int kt) {
        #pragma unroll
        for (int ii = 0; ii < 2; ++ii) {
            const int idx = w * 2 + ii;          // 0..3
            gload_lds16(kg + (size_t)(kt + idx * 8) * DD, &Ks[buf][idx * 512]);
            gload_lds16(vg + (size_t)(idx * 16) * SS + kt, &Vs[buf][idx * 512]);
        }
    };

    f32x4 mbc[2];
    stage(0, 0);
    mbc[0] = *(const f32x4*)(mbb);
    mbc[1] = *(const f32x4*)(mbb + 16);
    __syncthreads();

    for (int t = 0; t < NT; ++t) {
        const int buf = t & 1;
        const int kt = t * KVB;
        if (t > 0) { WAITVM(2); __builtin_amdgcn_s_barrier(); }
        if (t + 1 < NT) stage(buf ^ 1, kt + KVB);

        // ---- QK^T (swapped): sc[st][nf] = D[key][q=l15], keys nf*16 + l4*4 + r ----
        const char* Kb = (const char*)&Ks[buf][0];
        bf16x8 kf[2][2];
        #pragma unroll
        for (int ks = 0; ks < 2; ++ks)
            #pragma unroll
            for (int nf = 0; nf < 2; ++nf) {
                const int row = nf * 16 + l15;
                kf[ks][nf] = *(const bf16x8*)(Kb + row * 128 +
                              ((ks * 64 + l4 * 16) ^ ((row & 7) << 4)));
            }
        f32x4 sc[2][2] = {};
        __builtin_amdgcn_s_setprio(1);
        #pragma unroll
        for (int ks = 0; ks < 2; ++ks)
            #pragma unroll
            for (int st = 0; st < 2; ++st)
                #pragma unroll
                for (int nf = 0; nf < 2; ++nf)
                    sc[st][nf] = __builtin_amdgcn_mfma_f32_16x16x32_bf16(
                        kf[ks][nf], qf[st][ks], sc[st][nf], 0, 0, 0);
        __builtin_amdgcn_s_setprio(0);

        // ---- softmax per set (log2 domain, defer-max); P -> LDS ----
        #pragma unroll
        for (int st = 0; st < 2; ++st) {
            float tm = -3e38f;
            #pragma unroll
            for (int nf = 0; nf < 2; ++nf)
                #pragma unroll
                for (int r = 0; r < 4; ++r) {
                    const float z = fmaf(sc[st][nf][r], CSC, mbc[nf][r]);
                    sc[st][nf][r] = z;
                    tm = fmaxf(tm, z);
                }
            if (__any(tm > m2[st] + 11.5f)) {    // rare after warm-up
                tm = fmaxf(tm, __shfl_xor(tm, 16, 64));
                tm = fmaxf(tm, __shfl_xor(tm, 32, 64));
                const float mn = fmaxf(fmaxf(tm, m2[st]), -60.f);
                const float fac = __builtin_amdgcn_exp2f(m2[st] - mn);
                m2[st] = mn;
                accl[st] *= fac;
                #pragma unroll
                for (int nf = 0; nf < 4; ++nf)
                    #pragma unroll
                    for (int r = 0; r < 4; ++r)
                        ctx[st][nf][r] *= fac;
            }
            char* Pw = (char*)&Plds[w][st][0] + l15 * 80;
            #pragma unroll
            for (int nf = 0; nf < 2; ++nf) {
                union { bh h4[4]; uint64_t u; } pk;
                #pragma unroll
                for (int r = 0; r < 4; ++r)
                    pk.h4[r] = (bh)__builtin_amdgcn_exp2f(sc[st][nf][r] - m2[st]);
                *(uint64_t*)(Pw + nf * 32 + l4 * 8) = pk.u;
            }
        }
        WAITLGKM0;
        bf16x8 pa[2];
        #pragma unroll
        for (int st = 0; st < 2; ++st)
            pa[st] = *(const bf16x8*)((const char*)&Plds[w][st][0] + l15 * 80 + l4 * 16);

        // ---- PV (swapped): ctx = D[dk][q=l15]; lrun via ones-MFMA ----
        const char* Vb = (const char*)&Vs[buf][0];
        bf16x8 vf[4];
        #pragma unroll
        for (int nf = 0; nf < 4; ++nf) {
            const int row = nf * 16 + l15;
            vf[nf] = *(const bf16x8*)(Vb + row * 64 + ((l4 ^ (l15 & 3)) << 4));
        }
        __builtin_amdgcn_s_setprio(1);
        #pragma unroll
        for (int st = 0; st < 2; ++st) {
            #pragma unroll
            for (int nf = 0; nf < 4; ++nf)
                ctx[st][nf] = __builtin_amdgcn_mfma_f32_16x16x32_bf16(
                    vf[nf], pa[st], ctx[st][nf], 0, 0, 0);
            accl[st] = __builtin_amdgcn_mfma_f32_16x16x32_bf16(
                ones, pa[st], accl[st], 0, 0, 0);
        }
        __builtin_amdgcn_s_setprio(0);

        if (t + 1 < NT) {                        // mask bias for t+1
            mbc[0] = *(const f32x4*)(mbb + kt + KVB);
            mbc[1] = *(const f32x4*)(mbb + kt + KVB + 16);
        }
    }

    // ---- epilogue: q = l15 (+st*16), dk = nf*16 + l4*4 + r ----
    #pragma unroll
    for (int st = 0; st < 2; ++st) {
        const float linv = 1.0f / accl[st][0];
        #pragma unroll
        for (int nf = 0; nf < 4; ++nf) {
            union { bh h4[4]; uint64_t u; } pk;
            #pragma unroll
            for (int r = 0; r < 4; ++r)
                pk.h4[r] = (bh)(ctx[st][nf][r] * linv);
            *(uint64_t*)(O + (size_t)(b * SS + q0 + st * 16 + l15) * DD +
                         h * 64 + nf * 16 + l4 * 4) = pk.u;
        }
    }
}

// ---------------- host launch ----------------
extern "C" void kernel_launch(void* const* d_in, const int* in_sizes, int n_in,
                              void* d_out, int out_size, void* d_ws, size_t ws_size,
                              hipStream_t stream) {
    const int*   seq  = (const int*)  d_in[0];
    const float* mask = (const float*)d_in[1];
    const float* pos  = (const float*)d_in[2];
    const float* emb  = (const float*)d_in[3];
    const float* wq = (const float*)d_in[4];  const float* bq = (const float*)d_in[5];
    const float* wk = (const float*)d_in[6];  const float* bk = (const float*)d_in[7];
    const float* wv = (const float*)d_in[8];  const float* bv = (const float*)d_in[9];
    const float* wo = (const float*)d_in[10]; const float* bo = (const float*)d_in[11];
    const float* ag = (const float*)d_in[12]; const float* ab = (const float*)d_in[13];
    const float* am = (const float*)d_in[14]; const float* av = (const float*)d_in[15];
    const float* d1w = (const float*)d_in[16]; const float* d1b = (const float*)d_in[17];
    const float* d2w = (const float*)d_in[18]; const float* d2b = (const float*)d_in[19];
    const float* fg = (const float*)d_in[20]; const float* fb = (const float*)d_in[21];
    const float* fm = (const float*)d_in[22]; const float* fv = (const float*)d_in[23];

    float* X = (float*)d_out;

    char* p = (char*)d_ws;
    auto take = [&](size_t n) { char* q = p; p += (n + 255) & ~(size_t)255; return q; };
    const size_t WE  = (size_t)LL * DD * DD;          // per-matrix weight elems
    const size_t WQE = (size_t)LL * 3 * DD * DD;      // fused QKV elems
    bh* wcat = (bh*)take(WQE * 2);
    bh* wot = (bh*)take(WE * 2);
    bh* w1t = (bh*)take(WE * 2);
    bh* w2t = (bh*)take(WE * 2);
    const size_t AE = (size_t)NTOK * DD;
    bh* xb   = (bh*)take(AE * 2);
    bh* qb   = (bh*)take(AE * 2);
    bh* kb   = (bh*)take(AE * 2);
    bh* ctxb = (bh*)take(AE * 2);
    bh* subb = (bh*)take(AE * 2);
    bh* h1b  = (bh*)take(AE * 2);
    bh* vT   = (bh*)take(AE * 2);
    float* mbias = (float*)take((size_t)BB * SS * 4);

    const int QKV_OS = 3 * DD * DD;                   // 1536*512 per layer
    wprep_all<<<dim3(16, 16, 24), dim3(32, 8), 0, stream>>>(
        wq, wk, wv, wo, d1w, d2w, wcat, wot, w1t, w2t);

    maskprep<<<dim3(BB * SS / 1024), dim3(256), 0, stream>>>(mask, mbias);
    embed_k<<<dim3(NTOK), dim3(128), 0, stream>>>(seq, emb, pos, xb);

    for (int l = 0; l < LL; ++l) {
        const size_t wof = (size_t)l * DD * DD;
        const int    bof = l * DD;
        gemm_qkv<<<dim3(1536), dim3(256), 0, stream>>>(
            xb, wcat + (size_t)l * QKV_OS, bq + bof, bk + bof, bv + bof, qb, kb, vT);
        flash_attn<<<dim3(1024), dim3(128), 0, stream>>>(qb, kb, vT, mbias, ctxb);
        gemm_ep<1, false><<<dim3(1024), dim3(256), 0, stream>>>(
            ctxb, wot + wof, bo + bof, subb, xb, nullptr,
            ag + bof, ab + bof, am + bof, av + bof);
        gemm_ep<2, false><<<dim3(1024), dim3(256), 0, stream>>>(
            subb, w1t + wof, d1b + bof, h1b, nullptr, nullptr,
            nullptr, nullptr, nullptr, nullptr);
        if (l + 1 < LL) {
            gemm_ep<1, false><<<dim3(1024), dim3(256), 0, stream>>>(
                h1b, w2t + wof, d2b + bof, xb, subb, nullptr,
                fg + bof, fb + bof, fm + bof, fv + bof);
        } else {
            gemm_ep<1, true><<<dim3(1024), dim3(256), 0, stream>>>(
                h1b, w2t + wof, d2b + bof, xb, subb, X,
                fg + bof, fb + bof, fm + bof, fv + bof);
        }
    }
}

// Round 7
// 434.073 us; speedup vs baseline: 1.3935x; 1.3935x over previous
//
#include <hip/hip_runtime.h>
#include <stdint.h>
#include <stddef.h>

// ---------------- problem constants ----------------
constexpr int BB = 4, SS = 2048, DD = 512, HH = 8, LL = 4;
constexpr int NTOK = BB * SS;          // 8192 tokens
constexpr float BN_EPS = 1e-3f;

using bh = __bf16;
typedef __bf16 bf16x8 __attribute__((ext_vector_type(8)));
typedef float  f32x4  __attribute__((ext_vector_type(4)));
typedef float  f32x16 __attribute__((ext_vector_type(16)));

#define DEV __device__ __forceinline__
#define WAITVM(n) asm volatile("s_waitcnt vmcnt(" #n ")" ::: "memory")
#define WAITLGKM0 asm volatile("s_waitcnt lgkmcnt(0)" ::: "memory")

DEV void gload_lds16(const void* g, void* l) {
    __builtin_amdgcn_global_load_lds(
        (const __attribute__((address_space(1))) void*)g,
        (__attribute__((address_space(3))) void*)l, 16, 0, 0);
}

// ---------------- weight prep (all 6 matrices, one dispatch) ----------------
__global__ void wprep_all(const float* __restrict__ wq, const float* __restrict__ wk,
                          const float* __restrict__ wv, const float* __restrict__ wo,
                          const float* __restrict__ d1, const float* __restrict__ d2,
                          bh* __restrict__ wcat, bh* __restrict__ wot,
                          bh* __restrict__ w1t, bh* __restrict__ w2t) {
    __shared__ float t[32][33];
    const int z = blockIdx.z;              // 0..23
    const int m = z >> 2, l = z & 3;
    constexpr int QOS = 3 * DD * DD;
    const float* src;
    bh* dst;
    switch (m) {
        case 0:  src = wq; dst = wcat + (size_t)l * QOS;               break;
        case 1:  src = wk; dst = wcat + (size_t)l * QOS + DD * DD;     break;
        case 2:  src = wv; dst = wcat + (size_t)l * QOS + 2 * DD * DD; break;
        case 3:  src = wo; dst = wot + (size_t)l * DD * DD;            break;
        case 4:  src = d1; dst = w1t + (size_t)l * DD * DD;            break;
        default: src = d2; dst = w2t + (size_t)l * DD * DD;            break;
    }
    src += (size_t)l * DD * DD;
    const int r0 = blockIdx.y * 32, c0 = blockIdx.x * 32;
    const int tx = threadIdx.x, ty = threadIdx.y;   // 32 x 8
    #pragma unroll
    for (int i = ty; i < 32; i += 8) t[i][tx] = src[(size_t)(r0 + i) * DD + c0 + tx];
    __syncthreads();
    #pragma unroll
    for (int i = ty; i < 32; i += 8) dst[(size_t)(c0 + i) * DD + r0 + tx] = (bh)t[tx][i];
}

// ---------------- mask bias: [B,S] f32 -> 0 / -1e30 ----------------
__global__ void maskprep(const float* __restrict__ mask, float* __restrict__ mb) {
    const int i = ((int)blockIdx.x * 256 + threadIdx.x) * 4;
    const float4 m4 = *(const float4*)(mask + i);
    float4 o;
    o.x = (m4.x == 0.f) ? -1e30f : 0.f;
    o.y = (m4.y == 0.f) ? -1e30f : 0.f;
    o.z = (m4.z == 0.f) ? -1e30f : 0.f;
    o.w = (m4.w == 0.f) ? -1e30f : 0.f;
    *(float4*)(mb + i) = o;
}

// ---------------- embedding + positional -> bf16 ----------------
__global__ void embed_k(const int* __restrict__ seq, const float* __restrict__ emb,
                        const float* __restrict__ pos, bh* __restrict__ xb) {
    const int m = blockIdx.x;                // 0..8191
    const int s = m & (SS - 1);
    const int tok = seq[m];
    const int d = threadIdx.x * 4;           // 128 threads * 4 floats
    const float4 e  = *(const float4*)(emb + (size_t)tok * DD + d);
    const float4 pz = *(const float4*)(pos + (size_t)s * DD + d);
    union { bh h[4]; uint64_t u; } pk;
    pk.h[0] = (bh)(e.x + pz.x); pk.h[1] = (bh)(e.y + pz.y);
    pk.h[2] = (bh)(e.z + pz.z); pk.h[3] = (bh)(e.w + pz.w);
    *(uint64_t*)(xb + (size_t)m * DD + d) = pk.u;
}

// ---------------- GEMM 64x64 tile (round-5 proven version) ----------------
// EP 1: t = resb + acc + bias; s = BN(t); outb = bf16(s); if WF32: Xo = s
// EP 2: outb = bf16(relu(acc + bias))
template <int EP, bool WF32>
__global__ __launch_bounds__(256, 4)
void gemm64(const bh* __restrict__ A, const bh* __restrict__ Bt,
            const float* __restrict__ bias, bh* __restrict__ outb,
            const bh* __restrict__ resb, float* __restrict__ Xo,
            const float* __restrict__ gamma, const float* __restrict__ beta,
            const float* __restrict__ mean, const float* __restrict__ var) {
    constexpr int BK = 64, NKT = DD / BK;        // 8 k-tiles
    __shared__ __align__(16) bh As[2][64 * BK];  // 2 x 8 KB
    __shared__ __align__(16) bh Bs[2][64 * BK];  // 2 x 8 KB

    const int tid = threadIdx.x;
    const int w = tid >> 6, lane = tid & 63;
    const int l15 = lane & 15, l4 = lane >> 4;
    const int i = (int)blockIdx.x;
    const int xcd = i & 7, j = i >> 3;           // j 0..127
    const int bm = xcd * 16 + (j >> 3);          // 0..127
    const int bn = j & 7;                        // 0..7
    const int m0 = bm * 64, n0 = bn * 64;
    const int wr = w >> 1, wc = w & 1;           // wave tile 32x32

    f32x4 acc[2][2] = {};
    const int sr = lane >> 3;
    const int cbx = (lane & 7) ^ sr;

    auto stage = [&](int buf, int kk) {
        #pragma unroll
        for (int ii = 0; ii < 2; ++ii) {
            const int idx = w * 2 + ii;
            const int r = idx * 8 + sr;
            gload_lds16(A + (size_t)(m0 + r) * DD + kk + 8 * cbx, &As[buf][idx * 512]);
            gload_lds16(Bt + (size_t)(n0 + r) * DD + kk + 8 * cbx, &Bs[buf][idx * 512]);
        }
    };

    stage(0, 0);
    __syncthreads();

    for (int kt = 0; kt < NKT; ++kt) {
        const int buf = kt & 1;
        if (kt > 0) { WAITVM(0); __builtin_amdgcn_s_barrier(); }
        if (kt + 1 < NKT) stage(buf ^ 1, (kt + 1) * BK);

        const char* Ab = (const char*)&As[buf][0];
        const char* Bb = (const char*)&Bs[buf][0];
        #pragma unroll
        for (int ks = 0; ks < 2; ++ks) {
            bf16x8 af[2], bfr[2];
            const int cby = ks * 64 + l4 * 16;
            #pragma unroll
            for (int mf = 0; mf < 2; ++mf) {
                const int row = wr * 32 + mf * 16 + l15;
                af[mf] = *(const bf16x8*)(Ab + row * 128 + (cby ^ ((row & 7) << 4)));
            }
            #pragma unroll
            for (int nf = 0; nf < 2; ++nf) {
                const int row = wc * 32 + nf * 16 + l15;
                bfr[nf] = *(const bf16x8*)(Bb + row * 128 + (cby ^ ((row & 7) << 4)));
            }
            __builtin_amdgcn_s_setprio(1);
            #pragma unroll
            for (int mf = 0; mf < 2; ++mf)
                #pragma unroll
                for (int nf = 0; nf < 2; ++nf)
                    acc[mf][nf] = __builtin_amdgcn_mfma_f32_16x16x32_bf16(
                        af[mf], bfr[nf], acc[mf][nf], 0, 0, 0);
            __builtin_amdgcn_s_setprio(0);
        }
    }

    #pragma unroll
    for (int nf = 0; nf < 2; ++nf) {
        const int n = n0 + wc * 32 + nf * 16 + l15;
        const float bi = bias[n];
        float g = 0.f, be = 0.f, mu = 0.f, iv = 0.f;
        if constexpr (EP == 1) {
            g = gamma[n]; be = beta[n]; mu = mean[n];
            iv = rsqrtf(var[n] + BN_EPS);
        }
        #pragma unroll
        for (int mf = 0; mf < 2; ++mf) {
            #pragma unroll
            for (int r = 0; r < 4; ++r) {
                const int m = m0 + wr * 32 + mf * 16 + l4 * 4 + r;
                const size_t off = (size_t)m * DD + n;
                const float v = acc[mf][nf][r] + bi;
                if constexpr (EP == 2) {
                    outb[off] = (bh)fmaxf(v, 0.f);
                } else {
                    const float t = (float)resb[off] + v;
                    const float s = (t - mu) * iv * g + be;
                    outb[off] = (bh)s;
                    if constexpr (WF32) Xo[off] = s;
                }
            }
        }
    }
}

// ---------------- fused QKV GEMM; K/V written in MFMA-fragment-blocked layout ----------
// K_blk chunk = (bh*64 + tile)*4 + s          : elem(lane,j) = K[key=l&31][dk=s*16+(l>>5)*8+j]
// V_blk chunk = (bh*64 + tile)*4 + half*2 + ks: elem(lane,j) = V[dk=32*half+(l&31)][key=ks*16+(l>>5)*8+j]
__global__ __launch_bounds__(256, 3)
void gemm_qkv(const bh* __restrict__ A, const bh* __restrict__ Bt,
              const float* __restrict__ bq, const float* __restrict__ bk,
              const float* __restrict__ bv,
              bh* __restrict__ qb, bh* __restrict__ kblk, bh* __restrict__ vblk) {
    constexpr int BM = 128, BN = 64, BK = 64, NKT = DD / BK;
    __shared__ __align__(16) bh As[2][BM * BK];
    __shared__ __align__(16) bh Bs[2][BN * BK];

    const int tid = threadIdx.x;
    const int w = tid >> 6, lane = tid & 63;
    const int l15 = lane & 15, l4 = lane >> 4;
    const int i = (int)blockIdx.x;
    const int xcd = i & 7, j = i >> 3;        // j 0..191
    const int bm = xcd * 8 + (j & 7);         // 0..63
    const int bn = j >> 3;                    // 0..23
    const int m0 = bm * BM, n0 = bn * BN;
    const int wr = w >> 1, wc = w & 1;

    f32x4 acc[4][2] = {};
    const int sr = lane >> 3;
    const int cbx = (lane & 7) ^ sr;

    auto stage = [&](int buf, int kk) {
        #pragma unroll
        for (int ii = 0; ii < 4; ++ii) {
            const int idx = w * 4 + ii;
            const int r = idx * 8 + sr;
            gload_lds16(A + (size_t)(m0 + r) * DD + kk + 8 * cbx, &As[buf][idx * 512]);
        }
        #pragma unroll
        for (int ii = 0; ii < 2; ++ii) {
            const int idx = w * 2 + ii;
            const int r = idx * 8 + sr;
            gload_lds16(Bt + (size_t)(n0 + r) * DD + kk + 8 * cbx, &Bs[buf][idx * 512]);
        }
    };

    stage(0, 0);
    stage(1, BK);

    for (int kt = 0; kt < NKT; ++kt) {
        const int buf = kt & 1;
        if (kt + 1 < NKT) { WAITVM(6); } else { WAITVM(0); }
        __builtin_amdgcn_s_barrier();

        const char* Ab = (const char*)&As[buf][0];
        const char* Bb = (const char*)&Bs[buf][0];
        #pragma unroll
        for (int ks = 0; ks < 2; ++ks) {
            bf16x8 af[4], bfr[2];
            const int cby = ks * 64 + l4 * 16;
            #pragma unroll
            for (int mf = 0; mf < 4; ++mf) {
                const int row = wr * 64 + mf * 16 + l15;
                af[mf] = *(const bf16x8*)(Ab + row * 128 + (cby ^ ((row & 7) << 4)));
            }
            #pragma unroll
            for (int nf = 0; nf < 2; ++nf) {
                const int row = wc * 32 + nf * 16 + l15;
                bfr[nf] = *(const bf16x8*)(Bb + row * 128 + (cby ^ ((row & 7) << 4)));
            }
            #pragma unroll
            for (int mf = 0; mf < 4; ++mf)
                #pragma unroll
                for (int nf = 0; nf < 2; ++nf)
                    acc[mf][nf] = __builtin_amdgcn_mfma_f32_16x16x32_bf16(
                        af[mf], bfr[nf], acc[mf][nf], 0, 0, 0);
        }
        WAITLGKM0;
        __builtin_amdgcn_s_barrier();
        if (kt + 2 < NKT) stage(buf, (kt + 2) * BK);
    }

    const int part = n0 >> 9;                 // uniform per block: 0=Q 1=K 2=V
    #pragma unroll
    for (int nf = 0; nf < 2; ++nf) {
        const int n = n0 + wc * 32 + nf * 16 + l15;
        const int nn = n & 511;
        const float bi = (part == 0 ? bq : part == 1 ? bk : bv)[nn];
        if (part == 0) {
            #pragma unroll
            for (int mf = 0; mf < 4; ++mf)
                #pragma unroll
                for (int r = 0; r < 4; ++r) {
                    const int m = m0 + wr * 64 + mf * 16 + l4 * 4 + r;
                    qb[(size_t)m * DD + nn] = (bh)(acc[mf][nf][r] + bi);
                }
        } else if (part == 1) {
            const int hh = nn >> 6, dk = nn & 63;
            const int s = dk >> 4, hib = (dk >> 3) & 1, jj = dk & 7;
            #pragma unroll
            for (int mf = 0; mf < 4; ++mf)
                #pragma unroll
                for (int r = 0; r < 4; ++r) {
                    const int m = m0 + wr * 64 + mf * 16 + l4 * 4 + r;
                    const int b2 = m >> 11, sq = m & (SS - 1);
                    const int tile = sq >> 5, key5 = sq & 31;
                    kblk[(size_t)(((b2 * HH + hh) * 64 + tile) * 4 + s) * 512 +
                         (key5 + 32 * hib) * 8 + jj] = (bh)(acc[mf][nf][r] + bi);
                }
        } else {
            const int hh = nn >> 6, dk = nn & 63;
            const int half = dk >> 5, lanelow = dk & 31;
            #pragma unroll
            for (int mf = 0; mf < 4; ++mf) {
                const int m = m0 + wr * 64 + mf * 16 + l4 * 4;   // key base, mult of 4
                const int b2 = m >> 11, sq = m & (SS - 1);
                const int tile = sq >> 5, key5 = sq & 31;
                const int ks = key5 >> 4, hib = (key5 >> 3) & 1, jb = key5 & 7;
                union { bh h4[4]; uint64_t u; } pk;
                #pragma unroll
                for (int r = 0; r < 4; ++r)
                    pk.h4[r] = (bh)(acc[mf][nf][r] + bi);
                *(uint64_t*)(vblk + (size_t)(((b2 * HH + hh) * 64 + tile) * 4 +
                             half * 2 + ks) * 512 + (lanelow + 32 * hib) * 8 + jb) = pk.u;
            }
        }
    }
}

// ---------------- flash attention v7: 32x32 MFMA, zero LDS, zero barriers ----------------
// grid 1024 (XCD-pinned), 2 waves x 32q = 64 q/block. K/V fragments loaded from blocked
// global layout (L2-resident), 1-tile register prefetch (2 named generations, static).
// Swapped MFMA; P stays in registers via cvt_pk_bf16 + permlane32_swap (T12).
__global__ __launch_bounds__(128, 2)
void flash_attn(const bh* __restrict__ Q, const bh* __restrict__ Kb_,
                const bh* __restrict__ Vb_, const float* __restrict__ mb,
                bh* __restrict__ O) {
    constexpr int KVB = 32, NT = SS / KVB;       // 64 tiles
    constexpr float CSC = 0.18033688f;           // 0.125 * log2(e)

    const int tid = threadIdx.x;
    const int w = tid >> 6, lane = tid & 63;
    const int l31 = lane & 31, hi = lane >> 5;

    const int i = (int)blockIdx.x;
    const int xcd = i & 7, j = i >> 3;           // j 0..127
    const int g = xcd * 4 + (j >> 5);            // (b,h) group 0..31
    const int qt = j & 31;
    const int h = g & 7, b = g >> 3;
    const int q0 = qt * 64 + w * 32;

    // Q B-frags: qf[s]: Q[q = q0 + l31][dk = s*16 + hi*8 + j]
    const bh* qp = Q + (size_t)(b * SS + q0 + l31) * DD + h * 64 + hi * 8;
    const bf16x8 qf0 = *(const bf16x8*)(qp);
    const bf16x8 qf1 = *(const bf16x8*)(qp + 16);
    const bf16x8 qf2 = *(const bf16x8*)(qp + 32);
    const bf16x8 qf3 = *(const bf16x8*)(qp + 48);

    const bh* kbase = Kb_ + (size_t)((b * HH + h) * 256) * 512 + lane * 8;
    const bh* vbase = Vb_ + (size_t)((b * HH + h) * 256) * 512 + lane * 8;
    const float* mbb = mb + (size_t)b * SS + hi * 4;

    f32x16 ctx0 = {}, ctx1 = {};
    float accl = 0.f, m2 = -3e38f;

    bf16x8 kA0, kA1, kA2, kA3, vA0, vA1, vA2, vA3;
    bf16x8 kB0, kB1, kB2, kB3, vB0, vB1, vB2, vB3;
    f32x4 mA0, mA1, mA2, mA3, mB0, mB1, mB2, mB3;

#define PREF(G, t) do {                                                   \
        const bh* kp_ = kbase + (size_t)(t) * 2048;                       \
        k##G##0 = *(const bf16x8*)(kp_);                                  \
        k##G##1 = *(const bf16x8*)(kp_ + 512);                            \
        k##G##2 = *(const bf16x8*)(kp_ + 1024);                           \
        k##G##3 = *(const bf16x8*)(kp_ + 1536);                           \
        const bh* vp_ = vbase + (size_t)(t) * 2048;                       \
        v##G##0 = *(const bf16x8*)(vp_);                                  \
        v##G##1 = *(const bf16x8*)(vp_ + 512);                            \
        v##G##2 = *(const bf16x8*)(vp_ + 1024);                           \
        v##G##3 = *(const bf16x8*)(vp_ + 1536);                           \
        const float* mp_ = mbb + (t) * KVB;                               \
        m##G##0 = *(const f32x4*)(mp_);                                   \
        m##G##1 = *(const f32x4*)(mp_ + 8);                               \
        m##G##2 = *(const f32x4*)(mp_ + 16);                              \
        m##G##3 = *(const f32x4*)(mp_ + 24);                              \
    } while (0)

    auto compute = [&](const bf16x8& K0, const bf16x8& K1, const bf16x8& K2, const bf16x8& K3,
                       const bf16x8& V0, const bf16x8& V1, const bf16x8& V2, const bf16x8& V3,
                       const f32x4& M0, const f32x4& M1, const f32x4& M2, const f32x4& M3) {
        // QK^T (swapped): sc = D[key][q=l31], key = kt + (r&3)+8*(r>>2)+4*hi
        f32x16 sc = {};
        __builtin_amdgcn_s_setprio(1);
        sc = __builtin_amdgcn_mfma_f32_32x32x16_bf16(K0, qf0, sc, 0, 0, 0);
        sc = __builtin_amdgcn_mfma_f32_32x32x16_bf16(K1, qf1, sc, 0, 0, 0);
        sc = __builtin_amdgcn_mfma_f32_32x32x16_bf16(K2, qf2, sc, 0, 0, 0);
        sc = __builtin_amdgcn_mfma_f32_32x32x16_bf16(K3, qf3, sc, 0, 0, 0);
        __builtin_amdgcn_s_setprio(0);

        const f32x4 mm[4] = {M0, M1, M2, M3};
        float z[16];
        float tm = -3e38f;
        #pragma unroll
        for (int qg = 0; qg < 4; ++qg)
            #pragma unroll
            for (int c = 0; c < 4; ++c) {
                const float zz = fmaf(sc[qg * 4 + c], CSC, mm[qg][c]);
                z[qg * 4 + c] = zz;
                tm = fmaxf(tm, zz);
            }
        if (__any(tm > m2 + 11.5f)) {            // rare after warm-up
            const float tp = fmaxf(tm, __shfl_xor(tm, 32, 64));
            const float mn = fmaxf(fmaxf(tp, m2), -60.f);
            const float fac = __builtin_amdgcn_exp2f(m2 - mn);
            m2 = mn;
            accl *= fac;
            #pragma unroll
            for (int r = 0; r < 16; ++r) { ctx0[r] *= fac; ctx1[r] *= fac; }
        }
        uint32_t pk[8];
        float ps = 0.f;
        #pragma unroll
        for (int i2 = 0; i2 < 8; ++i2) {
            const float p0 = __builtin_amdgcn_exp2f(z[2 * i2] - m2);
            const float p1 = __builtin_amdgcn_exp2f(z[2 * i2 + 1] - m2);
            ps += p0 + p1;
            asm("v_cvt_pk_bf16_f32 %0, %1, %2" : "=v"(pk[i2]) : "v"(p0), "v"(p1));
        }
        accl += ps;
        // halves exchange: after in-place swaps, pk[0..3] / pk[4..7] are PV B-frags ks=0 / ks=1
        asm("v_permlane32_swap_b32 %0, %1" : "+v"(pk[0]), "+v"(pk[2]));
        asm("v_permlane32_swap_b32 %0, %1" : "+v"(pk[1]), "+v"(pk[3]));
        asm("v_permlane32_swap_b32 %0, %1" : "+v"(pk[4]), "+v"(pk[6]));
        asm("v_permlane32_swap_b32 %0, %1" : "+v"(pk[5]), "+v"(pk[7]));
        union U { uint32_t d[4]; bf16x8 v; } u0, u1;
        u0.d[0] = pk[0]; u0.d[1] = pk[1]; u0.d[2] = pk[2]; u0.d[3] = pk[3];
        u1.d[0] = pk[4]; u1.d[1] = pk[5]; u1.d[2] = pk[6]; u1.d[3] = pk[7];
        __builtin_amdgcn_s_setprio(1);
        ctx0 = __builtin_amdgcn_mfma_f32_32x32x16_bf16(V0, u0.v, ctx0, 0, 0, 0);
        ctx0 = __builtin_amdgcn_mfma_f32_32x32x16_bf16(V1, u1.v, ctx0, 0, 0, 0);
        ctx1 = __builtin_amdgcn_mfma_f32_32x32x16_bf16(V2, u0.v, ctx1, 0, 0, 0);
        ctx1 = __builtin_amdgcn_mfma_f32_32x32x16_bf16(V3, u1.v, ctx1, 0, 0, 0);
        __builtin_amdgcn_s_setprio(0);
    };

    PREF(A, 0);
    for (int t = 0; t < NT; t += 2) {
        PREF(B, t + 1);
        compute(kA0, kA1, kA2, kA3, vA0, vA1, vA2, vA3, mA0, mA1, mA2, mA3);
        PREF(A, t + 2);   // tile NT reads into guard region (never used)
        compute(kB0, kB1, kB2, kB3, vB0, vB1, vB2, vB3, mB0, mB1, mB2, mB3);
    }
#undef PREF

    // epilogue: q = q0 + l31; dk = (r&3) + 8*(r>>2) + 4*hi + 32*half
    const float lr = accl + __shfl_xor(accl, 32, 64);
    const float linv = 1.0f / lr;
    bh* op = O + (size_t)(b * SS + q0 + l31) * DD + h * 64 + hi * 4;
    #pragma unroll
    for (int rg = 0; rg < 4; ++rg) {
        union { bh h4[4]; uint64_t u; } pk0, pk1;
        #pragma unroll
        for (int r = 0; r < 4; ++r) {
            pk0.h4[r] = (bh)(ctx0[rg * 4 + r] * linv);
            pk1.h4[r] = (bh)(ctx1[rg * 4 + r] * linv);
        }
        *(uint64_t*)(op + rg * 8) = pk0.u;
        *(uint64_t*)(op + 32 + rg * 8) = pk1.u;
    }
}

// ---------------- host launch ----------------
extern "C" void kernel_launch(void* const* d_in, const int* in_sizes, int n_in,
                              void* d_out, int out_size, void* d_ws, size_t ws_size,
                              hipStream_t stream) {
    const int*   seq  = (const int*)  d_in[0];
    const float* mask = (const float*)d_in[1];
    const float* pos  = (const float*)d_in[2];
    const float* emb  = (const float*)d_in[3];
    const float* wq = (const float*)d_in[4];  const float* bq = (const float*)d_in[5];
    const float* wk = (const float*)d_in[6];  const float* bk = (const float*)d_in[7];
    const float* wv = (const float*)d_in[8];  const float* bv = (const float*)d_in[9];
    const float* wo = (const float*)d_in[10]; const float* bo = (const float*)d_in[11];
    const float* ag = (const float*)d_in[12]; const float* ab = (const float*)d_in[13];
    const float* am = (const float*)d_in[14]; const float* av = (const float*)d_in[15];
    const float* d1w = (const float*)d_in[16]; const float* d1b = (const float*)d_in[17];
    const float* d2w = (const float*)d_in[18]; const float* d2b = (const float*)d_in[19];
    const float* fg = (const float*)d_in[20]; const float* fb = (const float*)d_in[21];
    const float* fm = (const float*)d_in[22]; const float* fv = (const float*)d_in[23];

    float* X = (float*)d_out;

    char* p = (char*)d_ws;
    auto take = [&](size_t n) { char* q = p; p += (n + 255) & ~(size_t)255; return q; };
    const size_t WE  = (size_t)LL * DD * DD;
    const size_t WQE = (size_t)LL * 3 * DD * DD;
    bh* wcat = (bh*)take(WQE * 2);
    bh* wot = (bh*)take(WE * 2);
    bh* w1t = (bh*)take(WE * 2);
    bh* w2t = (bh*)take(WE * 2);
    const size_t AE = (size_t)NTOK * DD;
    bh* xb   = (bh*)take(AE * 2);
    bh* qb   = (bh*)take(AE * 2);
    bh* kblk = (bh*)take(AE * 2);
    bh* vblk = (bh*)take(AE * 2);
    bh* ctxb = (bh*)take(AE * 2);
    bh* subb = (bh*)take(AE * 2);
    bh* h1b  = (bh*)take(AE * 2);
    float* mbias = (float*)take((size_t)BB * SS * 4);
    (void)take(16384);   // guard region for flash's harmless tail prefetch

    const int QKV_OS = 3 * DD * DD;
    wprep_all<<<dim3(16, 16, 24), dim3(32, 8), 0, stream>>>(
        wq, wk, wv, wo, d1w, d2w, wcat, wot, w1t, w2t);

    maskprep<<<dim3(BB * SS / 1024), dim3(256), 0, stream>>>(mask, mbias);
    embed_k<<<dim3(NTOK), dim3(128), 0, stream>>>(seq, emb, pos, xb);

    for (int l = 0; l < LL; ++l) {
        const size_t wof = (size_t)l * DD * DD;
        const int    bof = l * DD;
        gemm_qkv<<<dim3(1536), dim3(256), 0, stream>>>(
            xb, wcat + (size_t)l * QKV_OS, bq + bof, bk + bof, bv + bof, qb, kblk, vblk);
        flash_attn<<<dim3(1024), dim3(128), 0, stream>>>(qb, kblk, vblk, mbias, ctxb);
        gemm64<1, false><<<dim3(1024), dim3(256), 0, stream>>>(
            ctxb, wot + wof, bo + bof, subb, xb, nullptr,
            ag + bof, ab + bof, am + bof, av + bof);
        gemm64<2, false><<<dim3(1024), dim3(256), 0, stream>>>(
            subb, w1t + wof, d1b + bof, h1b, nullptr, nullptr,
            nullptr, nullptr, nullptr, nullptr);
        if (l + 1 < LL) {
            gemm64<1, false><<<dim3(1024), dim3(256), 0, stream>>>(
                h1b, w2t + wof, d2b + bof, xb, subb, nullptr,
                fg + bof, fb + bof, fm + bof, fv + bof);
        } else {
            gemm64<1, true><<<dim3(1024), dim3(256), 0, stream>>>(
                h1b, w2t + wof, d2b + bof, xb, subb, X,
                fg + bof, fb + bof, fm + bof, fv + bof);
        }
    }
}

// Round 8
// 432.664 us; speedup vs baseline: 1.3981x; 1.0033x over previous
//
#include <hip/hip_runtime.h>
#include <stdint.h>
#include <stddef.h>

// ---------------- problem constants ----------------
constexpr int BB = 4, SS = 2048, DD = 512, HH = 8, LL = 4;
constexpr int NTOK = BB * SS;          // 8192 tokens
constexpr float BN_EPS = 1e-3f;

using bh = __bf16;
typedef __bf16 bf16x8 __attribute__((ext_vector_type(8)));
typedef float  f32x4  __attribute__((ext_vector_type(4)));
typedef float  f32x16 __attribute__((ext_vector_type(16)));

#define DEV __device__ __forceinline__
#define WAITVM(n) asm volatile("s_waitcnt vmcnt(" #n ")" ::: "memory")
#define WAITLGKM0 asm volatile("s_waitcnt lgkmcnt(0)" ::: "memory")

DEV void gload_lds16(const void* g, void* l) {
    __builtin_amdgcn_global_load_lds(
        (const __attribute__((address_space(1))) void*)g,
        (__attribute__((address_space(3))) void*)l, 16, 0, 0);
}

// ---------------- weight prep (all 6 matrices, one dispatch) ----------------
__global__ void wprep_all(const float* __restrict__ wq, const float* __restrict__ wk,
                          const float* __restrict__ wv, const float* __restrict__ wo,
                          const float* __restrict__ d1, const float* __restrict__ d2,
                          bh* __restrict__ wcat, bh* __restrict__ wot,
                          bh* __restrict__ w1t, bh* __restrict__ w2t) {
    __shared__ float t[32][33];
    const int z = blockIdx.z;              // 0..23
    const int m = z >> 2, l = z & 3;
    constexpr int QOS = 3 * DD * DD;
    const float* src;
    bh* dst;
    switch (m) {
        case 0:  src = wq; dst = wcat + (size_t)l * QOS;               break;
        case 1:  src = wk; dst = wcat + (size_t)l * QOS + DD * DD;     break;
        case 2:  src = wv; dst = wcat + (size_t)l * QOS + 2 * DD * DD; break;
        case 3:  src = wo; dst = wot + (size_t)l * DD * DD;            break;
        case 4:  src = d1; dst = w1t + (size_t)l * DD * DD;            break;
        default: src = d2; dst = w2t + (size_t)l * DD * DD;            break;
    }
    src += (size_t)l * DD * DD;
    const int r0 = blockIdx.y * 32, c0 = blockIdx.x * 32;
    const int tx = threadIdx.x, ty = threadIdx.y;   // 32 x 8
    #pragma unroll
    for (int i = ty; i < 32; i += 8) t[i][tx] = src[(size_t)(r0 + i) * DD + c0 + tx];
    __syncthreads();
    #pragma unroll
    for (int i = ty; i < 32; i += 8) dst[(size_t)(c0 + i) * DD + r0 + tx] = (bh)t[tx][i];
}

// ---------------- mask bias: [B,S] f32 -> 0 / -1e30 ----------------
__global__ void maskprep(const float* __restrict__ mask, float* __restrict__ mb) {
    const int i = ((int)blockIdx.x * 256 + threadIdx.x) * 4;
    const float4 m4 = *(const float4*)(mask + i);
    float4 o;
    o.x = (m4.x == 0.f) ? -1e30f : 0.f;
    o.y = (m4.y == 0.f) ? -1e30f : 0.f;
    o.z = (m4.z == 0.f) ? -1e30f : 0.f;
    o.w = (m4.w == 0.f) ? -1e30f : 0.f;
    *(float4*)(mb + i) = o;
}

// ---------------- embedding + positional -> bf16 ----------------
__global__ void embed_k(const int* __restrict__ seq, const float* __restrict__ emb,
                        const float* __restrict__ pos, bh* __restrict__ xb) {
    const int m = blockIdx.x;                // 0..8191
    const int s = m & (SS - 1);
    const int tok = seq[m];
    const int d = threadIdx.x * 4;           // 128 threads * 4 floats
    const float4 e  = *(const float4*)(emb + (size_t)tok * DD + d);
    const float4 pz = *(const float4*)(pos + (size_t)s * DD + d);
    union { bh h[4]; uint64_t u; } pk;
    pk.h[0] = (bh)(e.x + pz.x); pk.h[1] = (bh)(e.y + pz.y);
    pk.h[2] = (bh)(e.z + pz.z); pk.h[3] = (bh)(e.w + pz.w);
    *(uint64_t*)(xb + (size_t)m * DD + d) = pk.u;
}

// ---------------- GEMM 64x64 tile (round-5 proven version) ----------------
// EP 1: t = resb + acc + bias; s = BN(t); outb = bf16(s); if WF32: Xo = s
// EP 2: outb = bf16(relu(acc + bias))
template <int EP, bool WF32>
__global__ __launch_bounds__(256, 4)
void gemm64(const bh* __restrict__ A, const bh* __restrict__ Bt,
            const float* __restrict__ bias, bh* __restrict__ outb,
            const bh* __restrict__ resb, float* __restrict__ Xo,
            const float* __restrict__ gamma, const float* __restrict__ beta,
            const float* __restrict__ mean, const float* __restrict__ var) {
    constexpr int BK = 64, NKT = DD / BK;        // 8 k-tiles
    __shared__ __align__(16) bh As[2][64 * BK];  // 2 x 8 KB
    __shared__ __align__(16) bh Bs[2][64 * BK];  // 2 x 8 KB

    const int tid = threadIdx.x;
    const int w = tid >> 6, lane = tid & 63;
    const int l15 = lane & 15, l4 = lane >> 4;
    const int i = (int)blockIdx.x;
    const int xcd = i & 7, j = i >> 3;           // j 0..127
    const int bm = xcd * 16 + (j >> 3);          // 0..127
    const int bn = j & 7;                        // 0..7
    const int m0 = bm * 64, n0 = bn * 64;
    const int wr = w >> 1, wc = w & 1;           // wave tile 32x32

    f32x4 acc[2][2] = {};
    const int sr = lane >> 3;
    const int cbx = (lane & 7) ^ sr;

    auto stage = [&](int buf, int kk) {
        #pragma unroll
        for (int ii = 0; ii < 2; ++ii) {
            const int idx = w * 2 + ii;
            const int r = idx * 8 + sr;
            gload_lds16(A + (size_t)(m0 + r) * DD + kk + 8 * cbx, &As[buf][idx * 512]);
            gload_lds16(Bt + (size_t)(n0 + r) * DD + kk + 8 * cbx, &Bs[buf][idx * 512]);
        }
    };

    stage(0, 0);
    __syncthreads();

    for (int kt = 0; kt < NKT; ++kt) {
        const int buf = kt & 1;
        if (kt > 0) { WAITVM(0); __builtin_amdgcn_s_barrier(); }
        if (kt + 1 < NKT) stage(buf ^ 1, (kt + 1) * BK);

        const char* Ab = (const char*)&As[buf][0];
        const char* Bb = (const char*)&Bs[buf][0];
        #pragma unroll
        for (int ks = 0; ks < 2; ++ks) {
            bf16x8 af[2], bfr[2];
            const int cby = ks * 64 + l4 * 16;
            #pragma unroll
            for (int mf = 0; mf < 2; ++mf) {
                const int row = wr * 32 + mf * 16 + l15;
                af[mf] = *(const bf16x8*)(Ab + row * 128 + (cby ^ ((row & 7) << 4)));
            }
            #pragma unroll
            for (int nf = 0; nf < 2; ++nf) {
                const int row = wc * 32 + nf * 16 + l15;
                bfr[nf] = *(const bf16x8*)(Bb + row * 128 + (cby ^ ((row & 7) << 4)));
            }
            __builtin_amdgcn_s_setprio(1);
            #pragma unroll
            for (int mf = 0; mf < 2; ++mf)
                #pragma unroll
                for (int nf = 0; nf < 2; ++nf)
                    acc[mf][nf] = __builtin_amdgcn_mfma_f32_16x16x32_bf16(
                        af[mf], bfr[nf], acc[mf][nf], 0, 0, 0);
            __builtin_amdgcn_s_setprio(0);
        }
    }

    #pragma unroll
    for (int nf = 0; nf < 2; ++nf) {
        const int n = n0 + wc * 32 + nf * 16 + l15;
        const float bi = bias[n];
        float g = 0.f, be = 0.f, mu = 0.f, iv = 0.f;
        if constexpr (EP == 1) {
            g = gamma[n]; be = beta[n]; mu = mean[n];
            iv = rsqrtf(var[n] + BN_EPS);
        }
        #pragma unroll
        for (int mf = 0; mf < 2; ++mf) {
            #pragma unroll
            for (int r = 0; r < 4; ++r) {
                const int m = m0 + wr * 32 + mf * 16 + l4 * 4 + r;
                const size_t off = (size_t)m * DD + n;
                const float v = acc[mf][nf][r] + bi;
                if constexpr (EP == 2) {
                    outb[off] = (bh)fmaxf(v, 0.f);
                } else {
                    const float t = (float)resb[off] + v;
                    const float s = (t - mu) * iv * g + be;
                    outb[off] = (bh)s;
                    if constexpr (WF32) Xo[off] = s;
                }
            }
        }
    }
}

// ---------------- fused QKV GEMM; K/V written in MFMA-fragment-blocked layout ----------
// K_blk chunk = (bh*64 + tile)*4 + s          : elem(lane,j) = K[key=l&31][dk=s*16+(l>>5)*8+j]
// V_blk chunk = (bh*64 + tile)*4 + half*2 + ks: elem(lane,j) = V[dk=32*half+(l&31)][key=ks*16+(l>>5)*8+j]
__global__ __launch_bounds__(256, 3)
void gemm_qkv(const bh* __restrict__ A, const bh* __restrict__ Bt,
              const float* __restrict__ bq, const float* __restrict__ bk,
              const float* __restrict__ bv,
              bh* __restrict__ qb, bh* __restrict__ kblk, bh* __restrict__ vblk) {
    constexpr int BM = 128, BN = 64, BK = 64, NKT = DD / BK;
    __shared__ __align__(16) bh As[2][BM * BK];
    __shared__ __align__(16) bh Bs[2][BN * BK];

    const int tid = threadIdx.x;
    const int w = tid >> 6, lane = tid & 63;
    const int l15 = lane & 15, l4 = lane >> 4;
    const int i = (int)blockIdx.x;
    const int xcd = i & 7, j = i >> 3;        // j 0..191
    const int bm = xcd * 8 + (j & 7);         // 0..63
    const int bn = j >> 3;                    // 0..23
    const int m0 = bm * BM, n0 = bn * BN;
    const int wr = w >> 1, wc = w & 1;

    f32x4 acc[4][2] = {};
    const int sr = lane >> 3;
    const int cbx = (lane & 7) ^ sr;

    auto stage = [&](int buf, int kk) {
        #pragma unroll
        for (int ii = 0; ii < 4; ++ii) {
            const int idx = w * 4 + ii;
            const int r = idx * 8 + sr;
            gload_lds16(A + (size_t)(m0 + r) * DD + kk + 8 * cbx, &As[buf][idx * 512]);
        }
        #pragma unroll
        for (int ii = 0; ii < 2; ++ii) {
            const int idx = w * 2 + ii;
            const int r = idx * 8 + sr;
            gload_lds16(Bt + (size_t)(n0 + r) * DD + kk + 8 * cbx, &Bs[buf][idx * 512]);
        }
    };

    stage(0, 0);
    stage(1, BK);

    for (int kt = 0; kt < NKT; ++kt) {
        const int buf = kt & 1;
        if (kt + 1 < NKT) { WAITVM(6); } else { WAITVM(0); }
        __builtin_amdgcn_s_barrier();

        const char* Ab = (const char*)&As[buf][0];
        const char* Bb = (const char*)&Bs[buf][0];
        #pragma unroll
        for (int ks = 0; ks < 2; ++ks) {
            bf16x8 af[4], bfr[2];
            const int cby = ks * 64 + l4 * 16;
            #pragma unroll
            for (int mf = 0; mf < 4; ++mf) {
                const int row = wr * 64 + mf * 16 + l15;
                af[mf] = *(const bf16x8*)(Ab + row * 128 + (cby ^ ((row & 7) << 4)));
            }
            #pragma unroll
            for (int nf = 0; nf < 2; ++nf) {
                const int row = wc * 32 + nf * 16 + l15;
                bfr[nf] = *(const bf16x8*)(Bb + row * 128 + (cby ^ ((row & 7) << 4)));
            }
            #pragma unroll
            for (int mf = 0; mf < 4; ++mf)
                #pragma unroll
                for (int nf = 0; nf < 2; ++nf)
                    acc[mf][nf] = __builtin_amdgcn_mfma_f32_16x16x32_bf16(
                        af[mf], bfr[nf], acc[mf][nf], 0, 0, 0);
        }
        WAITLGKM0;
        __builtin_amdgcn_s_barrier();
        if (kt + 2 < NKT) stage(buf, (kt + 2) * BK);
    }

    const int part = n0 >> 9;                 // uniform per block: 0=Q 1=K 2=V
    #pragma unroll
    for (int nf = 0; nf < 2; ++nf) {
        const int n = n0 + wc * 32 + nf * 16 + l15;
        const int nn = n & 511;
        const float bi = (part == 0 ? bq : part == 1 ? bk : bv)[nn];
        if (part == 0) {
            #pragma unroll
            for (int mf = 0; mf < 4; ++mf)
                #pragma unroll
                for (int r = 0; r < 4; ++r) {
                    const int m = m0 + wr * 64 + mf * 16 + l4 * 4 + r;
                    qb[(size_t)m * DD + nn] = (bh)(acc[mf][nf][r] + bi);
                }
        } else if (part == 1) {
            const int hh = nn >> 6, dk = nn & 63;
            const int s = dk >> 4, hib = (dk >> 3) & 1, jj = dk & 7;
            #pragma unroll
            for (int mf = 0; mf < 4; ++mf)
                #pragma unroll
                for (int r = 0; r < 4; ++r) {
                    const int m = m0 + wr * 64 + mf * 16 + l4 * 4 + r;
                    const int b2 = m >> 11, sq = m & (SS - 1);
                    const int tile = sq >> 5, key5 = sq & 31;
                    kblk[(size_t)(((b2 * HH + hh) * 64 + tile) * 4 + s) * 512 +
                         (key5 + 32 * hib) * 8 + jj] = (bh)(acc[mf][nf][r] + bi);
                }
        } else {
            const int hh = nn >> 6, dk = nn & 63;
            const int half = dk >> 5, lanelow = dk & 31;
            #pragma unroll
            for (int mf = 0; mf < 4; ++mf) {
                const int m = m0 + wr * 64 + mf * 16 + l4 * 4;   // key base, mult of 4
                const int b2 = m >> 11, sq = m & (SS - 1);
                const int tile = sq >> 5, key5 = sq & 31;
                const int ks = key5 >> 4, hib = (key5 >> 3) & 1, jb = key5 & 7;
                union { bh h4[4]; uint64_t u; } pk;
                #pragma unroll
                for (int r = 0; r < 4; ++r)
                    pk.h4[r] = (bh)(acc[mf][nf][r] + bi);
                *(uint64_t*)(vblk + (size_t)(((b2 * HH + hh) * 64 + tile) * 4 +
                             half * 2 + ks) * 512 + (lanelow + 32 * hib) * 8 + jb) = pk.u;
            }
        }
    }
}

// ---------------- flash attention v7: 32x32 MFMA, zero LDS, zero barriers ----------------
// grid 1024 (XCD-pinned), 2 waves x 32q = 64 q/block. K/V fragments loaded from blocked
// global layout (L2-resident), 1-tile register prefetch (2 named generations, static).
// Swapped MFMA; P stays in registers via cvt_pk_bf16 + permlane32_swap (T12).
__global__ __launch_bounds__(128, 2)
void flash_attn(const bh* __restrict__ Q, const bh* __restrict__ Kb_,
                const bh* __restrict__ Vb_, const float* __restrict__ mb,
                bh* __restrict__ O) {
    constexpr int KVB = 32, NT = SS / KVB;       // 64 tiles
    constexpr float CSC = 0.18033688f;           // 0.125 * log2(e)

    const int tid = threadIdx.x;
    const int w = tid >> 6, lane = tid & 63;
    const int l31 = lane & 31, hi = lane >> 5;

    const int i = (int)blockIdx.x;
    const int xcd = i & 7, j = i >> 3;           // j 0..127
    const int g = xcd * 4 + (j >> 5);            // (b,h) group 0..31
    const int qt = j & 31;
    const int h = g & 7, b = g >> 3;
    const int q0 = qt * 64 + w * 32;

    // Q B-frags: qf[s]: Q[q = q0 + l31][dk = s*16 + hi*8 + j]
    const bh* qp = Q + (size_t)(b * SS + q0 + l31) * DD + h * 64 + hi * 8;
    const bf16x8 qf0 = *(const bf16x8*)(qp);
    const bf16x8 qf1 = *(const bf16x8*)(qp + 16);
    const bf16x8 qf2 = *(const bf16x8*)(qp + 32);
    const bf16x8 qf3 = *(const bf16x8*)(qp + 48);

    const bh* kbase = Kb_ + (size_t)((b * HH + h) * 256) * 512 + lane * 8;
    const bh* vbase = Vb_ + (size_t)((b * HH + h) * 256) * 512 + lane * 8;
    const float* mbb = mb + (size_t)b * SS + hi * 4;

    f32x16 ctx0 = {}, ctx1 = {};
    float accl = 0.f, m2 = -3e38f;

    bf16x8 kA0, kA1, kA2, kA3, vA0, vA1, vA2, vA3;
    bf16x8 kB0, kB1, kB2, kB3, vB0, vB1, vB2, vB3;
    f32x4 mA0, mA1, mA2, mA3, mB0, mB1, mB2, mB3;

#define PREF(G, t) do {                                                   \
        const bh* kp_ = kbase + (size_t)(t) * 2048;                       \
        k##G##0 = *(const bf16x8*)(kp_);                                  \
        k##G##1 = *(const bf16x8*)(kp_ + 512);                            \
        k##G##2 = *(const bf16x8*)(kp_ + 1024);                           \
        k##G##3 = *(const bf16x8*)(kp_ + 1536);                           \
        const bh* vp_ = vbase + (size_t)(t) * 2048;                       \
        v##G##0 = *(const bf16x8*)(vp_);                                  \
        v##G##1 = *(const bf16x8*)(vp_ + 512);                            \
        v##G##2 = *(const bf16x8*)(vp_ + 1024);                           \
        v##G##3 = *(const bf16x8*)(vp_ + 1536);                           \
        const float* mp_ = mbb + (t) * KVB;                               \
        m##G##0 = *(const f32x4*)(mp_);                                   \
        m##G##1 = *(const f32x4*)(mp_ + 8);                               \
        m##G##2 = *(const f32x4*)(mp_ + 16);                              \
        m##G##3 = *(const f32x4*)(mp_ + 24);                              \
    } while (0)

    auto compute = [&](const bf16x8& K0, const bf16x8& K1, const bf16x8& K2, const bf16x8& K3,
                       const bf16x8& V0, const bf16x8& V1, const bf16x8& V2, const bf16x8& V3,
                       const f32x4& M0, const f32x4& M1, const f32x4& M2, const f32x4& M3) {
        // QK^T (swapped): sc = D[key][q=l31], key = kt + (r&3)+8*(r>>2)+4*hi
        f32x16 sc = {};
        __builtin_amdgcn_s_setprio(1);
        sc = __builtin_amdgcn_mfma_f32_32x32x16_bf16(K0, qf0, sc, 0, 0, 0);
        sc = __builtin_amdgcn_mfma_f32_32x32x16_bf16(K1, qf1, sc, 0, 0, 0);
        sc = __builtin_amdgcn_mfma_f32_32x32x16_bf16(K2, qf2, sc, 0, 0, 0);
        sc = __builtin_amdgcn_mfma_f32_32x32x16_bf16(K3, qf3, sc, 0, 0, 0);
        __builtin_amdgcn_s_setprio(0);

        const f32x4 mm[4] = {M0, M1, M2, M3};
        float z[16];
        float tm = -3e38f;
        #pragma unroll
        for (int qg = 0; qg < 4; ++qg)
            #pragma unroll
            for (int c = 0; c < 4; ++c) {
                const float zz = fmaf(sc[qg * 4 + c], CSC, mm[qg][c]);
                z[qg * 4 + c] = zz;
                tm = fmaxf(tm, zz);
            }
        if (__any(tm > m2 + 11.5f)) {            // rare after warm-up
            const float tp = fmaxf(tm, __shfl_xor(tm, 32, 64));
            const float mn = fmaxf(fmaxf(tp, m2), -60.f);
            const float fac = __builtin_amdgcn_exp2f(m2 - mn);
            m2 = mn;
            accl *= fac;
            #pragma unroll
            for (int r = 0; r < 16; ++r) { ctx0[r] *= fac; ctx1[r] *= fac; }
        }
        uint32_t pk[8];
        float ps = 0.f;
        #pragma unroll
        for (int i2 = 0; i2 < 8; ++i2) {
            const float p0 = __builtin_amdgcn_exp2f(z[2 * i2] - m2);
            const float p1 = __builtin_amdgcn_exp2f(z[2 * i2 + 1] - m2);
            ps += p0 + p1;
            asm("v_cvt_pk_bf16_f32 %0, %1, %2" : "=v"(pk[i2]) : "v"(p0), "v"(p1));
        }
        accl += ps;
        // halves exchange: after in-place swaps, pk[0..3] / pk[4..7] are PV B-frags ks=0 / ks=1
        asm("v_permlane32_swap_b32 %0, %1" : "+v"(pk[0]), "+v"(pk[2]));
        asm("v_permlane32_swap_b32 %0, %1" : "+v"(pk[1]), "+v"(pk[3]));
        asm("v_permlane32_swap_b32 %0, %1" : "+v"(pk[4]), "+v"(pk[6]));
        asm("v_permlane32_swap_b32 %0, %1" : "+v"(pk[5]), "+v"(pk[7]));
        union U { uint32_t d[4]; bf16x8 v; } u0, u1;
        u0.d[0] = pk[0]; u0.d[1] = pk[1]; u0.d[2] = pk[2]; u0.d[3] = pk[3];
        u1.d[0] = pk[4]; u1.d[1] = pk[5]; u1.d[2] = pk[6]; u1.d[3] = pk[7];
        __builtin_amdgcn_s_setprio(1);
        ctx0 = __builtin_amdgcn_mfma_f32_32x32x16_bf16(V0, u0.v, ctx0, 0, 0, 0);
        ctx0 = __builtin_amdgcn_mfma_f32_32x32x16_bf16(V1, u1.v, ctx0, 0, 0, 0);
        ctx1 = __builtin_amdgcn_mfma_f32_32x32x16_bf16(V2, u0.v, ctx1, 0, 0, 0);
        ctx1 = __builtin_amdgcn_mfma_f32_32x32x16_bf16(V3, u1.v, ctx1, 0, 0, 0);
        __builtin_amdgcn_s_setprio(0);
    };

    PREF(A, 0);
    for (int t = 0; t < NT; t += 2) {
        PREF(B, t + 1);
        compute(kA0, kA1, kA2, kA3, vA0, vA1, vA2, vA3, mA0, mA1, mA2, mA3);
        PREF(A, t + 2);   // tile NT reads into guard region (never used)
        compute(kB0, kB1, kB2, kB3, vB0, vB1, vB2, vB3, mB0, mB1, mB2, mB3);
    }
#undef PREF

    // epilogue: q = q0 + l31; dk = (r&3) + 8*(r>>2) + 4*hi + 32*half
    const float lr = accl + __shfl_xor(accl, 32, 64);
    const float linv = 1.0f / lr;
    bh* op = O + (size_t)(b * SS + q0 + l31) * DD + h * 64 + hi * 4;
    #pragma unroll
    for (int rg = 0; rg < 4; ++rg) {
        union { bh h4[4]; uint64_t u; } pk0, pk1;
        #pragma unroll
        for (int r = 0; r < 4; ++r) {
            pk0.h4[r] = (bh)(ctx0[rg * 4 + r] * linv);
            pk1.h4[r] = (bh)(ctx1[rg * 4 + r] * linv);
        }
        *(uint64_t*)(op + rg * 8) = pk0.u;
        *(uint64_t*)(op + 32 + rg * 8) = pk1.u;
    }
}

// ---------------- host launch ----------------
extern "C" void kernel_launch(void* const* d_in, const int* in_sizes, int n_in,
                              void* d_out, int out_size, void* d_ws, size_t ws_size,
                              hipStream_t stream) {
    const int*   seq  = (const int*)  d_in[0];
    const float* mask = (const float*)d_in[1];
    const float* pos  = (const float*)d_in[2];
    const float* emb  = (const float*)d_in[3];
    const float* wq = (const float*)d_in[4];  const float* bq = (const float*)d_in[5];
    const float* wk = (const float*)d_in[6];  const float* bk = (const float*)d_in[7];
    const float* wv = (const float*)d_in[8];  const float* bv = (const float*)d_in[9];
    const float* wo = (const float*)d_in[10]; const float* bo = (const float*)d_in[11];
    const float* ag = (const float*)d_in[12]; const float* ab = (const float*)d_in[13];
    const float* am = (const float*)d_in[14]; const float* av = (const float*)d_in[15];
    const float* d1w = (const float*)d_in[16]; const float* d1b = (const float*)d_in[17];
    const float* d2w = (const float*)d_in[18]; const float* d2b = (const float*)d_in[19];
    const float* fg = (const float*)d_in[20]; const float* fb = (const float*)d_in[21];
    const float* fm = (const float*)d_in[22]; const float* fv = (const float*)d_in[23];

    float* X = (float*)d_out;

    char* p = (char*)d_ws;
    auto take = [&](size_t n) { char* q = p; p += (n + 255) & ~(size_t)255; return q; };
    const size_t WE  = (size_t)LL * DD * DD;
    const size_t WQE = (size_t)LL * 3 * DD * DD;
    bh* wcat = (bh*)take(WQE * 2);
    bh* wot = (bh*)take(WE * 2);
    bh* w1t = (bh*)take(WE * 2);
    bh* w2t = (bh*)take(WE * 2);
    const size_t AE = (size_t)NTOK * DD;
    bh* xb   = (bh*)take(AE * 2);
    bh* qb   = (bh*)take(AE * 2);
    bh* kblk = (bh*)take(AE * 2);
    bh* vblk = (bh*)take(AE * 2);
    bh* ctxb = (bh*)take(AE * 2);
    bh* subb = (bh*)take(AE * 2);
    bh* h1b  = (bh*)take(AE * 2);
    float* mbias = (float*)take((size_t)BB * SS * 4);
    (void)take(16384);   // guard region for flash's harmless tail prefetch

    const int QKV_OS = 3 * DD * DD;
    wprep_all<<<dim3(16, 16, 24), dim3(32, 8), 0, stream>>>(
        wq, wk, wv, wo, d1w, d2w, wcat, wot, w1t, w2t);

    maskprep<<<dim3(BB * SS / 1024), dim3(256), 0, stream>>>(mask, mbias);
    embed_k<<<dim3(NTOK), dim3(128), 0, stream>>>(seq, emb, pos, xb);

    for (int l = 0; l < LL; ++l) {
        const size_t wof = (size_t)l * DD * DD;
        const int    bof = l * DD;
        gemm_qkv<<<dim3(1536), dim3(256), 0, stream>>>(
            xb, wcat + (size_t)l * QKV_OS, bq + bof, bk + bof, bv + bof, qb, kblk, vblk);
        flash_attn<<<dim3(1024), dim3(128), 0, stream>>>(qb, kblk, vblk, mbias, ctxb);
        gemm64<1, false><<<dim3(1024), dim3(256), 0, stream>>>(
            ctxb, wot + wof, bo + bof, subb, xb, nullptr,
            ag + bof, ab + bof, am + bof, av + bof);
        gemm64<2, false><<<dim3(1024), dim3(256), 0, stream>>>(
            subb, w1t + wof, d1b + bof, h1b, nullptr, nullptr,
            nullptr, nullptr, nullptr, nullptr);
        if (l + 1 < LL) {
            gemm64<1, false><<<dim3(1024), dim3(256), 0, stream>>>(
                h1b, w2t + wof, d2b + bof, xb, subb, nullptr,
                fg + bof, fb + bof, fm + bof, fv + bof);
        } else {
            gemm64<1, true><<<dim3(1024), dim3(256), 0, stream>>>(
                h1b, w2t + wof, d2b + bof, xb, subb, X,
                fg + bof, fb + bof, fm + bof, fv + bof);
        }
    }
}

// Round 9
// 432.596 us; speedup vs baseline: 1.3983x; 1.0002x over previous
//
#include <hip/hip_runtime.h>
#include <stdint.h>
#include <stddef.h>

// ---------------- problem constants ----------------
constexpr int BB = 4, SS = 2048, DD = 512, HH = 8, LL = 4;
constexpr int NTOK = BB * SS;          // 8192 tokens
constexpr float BN_EPS = 1e-3f;

using bh = __bf16;
typedef __bf16 bf16x8 __attribute__((ext_vector_type(8)));
typedef float  f32x4  __attribute__((ext_vector_type(4)));
typedef float  f32x16 __attribute__((ext_vector_type(16)));

#define DEV __device__ __forceinline__
#define WAITVM(n) asm volatile("s_waitcnt vmcnt(" #n ")" ::: "memory")
#define WAITLGKM0 asm volatile("s_waitcnt lgkmcnt(0)" ::: "memory")

DEV void gload_lds16(const void* g, void* l) {
    __builtin_amdgcn_global_load_lds(
        (const __attribute__((address_space(1))) void*)g,
        (__attribute__((address_space(3))) void*)l, 16, 0, 0);
}

// ---------------- weight prep (all 6 matrices, one dispatch) ----------------
__global__ void wprep_all(const float* __restrict__ wq, const float* __restrict__ wk,
                          const float* __restrict__ wv, const float* __restrict__ wo,
                          const float* __restrict__ d1, const float* __restrict__ d2,
                          bh* __restrict__ wcat, bh* __restrict__ wot,
                          bh* __restrict__ w1t, bh* __restrict__ w2t) {
    __shared__ float t[32][33];
    const int z = blockIdx.z;              // 0..23
    const int m = z >> 2, l = z & 3;
    constexpr int QOS = 3 * DD * DD;
    const float* src;
    bh* dst;
    switch (m) {
        case 0:  src = wq; dst = wcat + (size_t)l * QOS;               break;
        case 1:  src = wk; dst = wcat + (size_t)l * QOS + DD * DD;     break;
        case 2:  src = wv; dst = wcat + (size_t)l * QOS + 2 * DD * DD; break;
        case 3:  src = wo; dst = wot + (size_t)l * DD * DD;            break;
        case 4:  src = d1; dst = w1t + (size_t)l * DD * DD;            break;
        default: src = d2; dst = w2t + (size_t)l * DD * DD;            break;
    }
    src += (size_t)l * DD * DD;
    const int r0 = blockIdx.y * 32, c0 = blockIdx.x * 32;
    const int tx = threadIdx.x, ty = threadIdx.y;   // 32 x 8
    #pragma unroll
    for (int i = ty; i < 32; i += 8) t[i][tx] = src[(size_t)(r0 + i) * DD + c0 + tx];
    __syncthreads();
    #pragma unroll
    for (int i = ty; i < 32; i += 8) dst[(size_t)(c0 + i) * DD + r0 + tx] = (bh)t[tx][i];
}

// ---------------- mask bias: [B,S] f32 -> 0 / -1e30 ----------------
__global__ void maskprep(const float* __restrict__ mask, float* __restrict__ mb) {
    const int i = ((int)blockIdx.x * 256 + threadIdx.x) * 4;
    const float4 m4 = *(const float4*)(mask + i);
    float4 o;
    o.x = (m4.x == 0.f) ? -1e30f : 0.f;
    o.y = (m4.y == 0.f) ? -1e30f : 0.f;
    o.z = (m4.z == 0.f) ? -1e30f : 0.f;
    o.w = (m4.w == 0.f) ? -1e30f : 0.f;
    *(float4*)(mb + i) = o;
}

// ---------------- embedding + positional -> bf16 ----------------
__global__ void embed_k(const int* __restrict__ seq, const float* __restrict__ emb,
                        const float* __restrict__ pos, bh* __restrict__ xb) {
    const int m = blockIdx.x;                // 0..8191
    const int s = m & (SS - 1);
    const int tok = seq[m];
    const int d = threadIdx.x * 4;           // 128 threads * 4 floats
    const float4 e  = *(const float4*)(emb + (size_t)tok * DD + d);
    const float4 pz = *(const float4*)(pos + (size_t)s * DD + d);
    union { bh h[4]; uint64_t u; } pk;
    pk.h[0] = (bh)(e.x + pz.x); pk.h[1] = (bh)(e.y + pz.y);
    pk.h[2] = (bh)(e.z + pz.z); pk.h[3] = (bh)(e.w + pz.w);
    *(uint64_t*)(xb + (size_t)m * DD + d) = pk.u;
}

// ---------------- GEMM 64x64 tile (round-5 proven version) ----------------
// EP 1: t = resb + acc + bias; s = BN(t); outb = bf16(s); if WF32: Xo = s
// EP 2: outb = bf16(relu(acc + bias))
template <int EP, bool WF32>
__global__ __launch_bounds__(256, 4)
void gemm64(const bh* __restrict__ A, const bh* __restrict__ Bt,
            const float* __restrict__ bias, bh* __restrict__ outb,
            const bh* __restrict__ resb, float* __restrict__ Xo,
            const float* __restrict__ gamma, const float* __restrict__ beta,
            const float* __restrict__ mean, const float* __restrict__ var) {
    constexpr int BK = 64, NKT = DD / BK;        // 8 k-tiles
    __shared__ __align__(16) bh As[2][64 * BK];  // 2 x 8 KB
    __shared__ __align__(16) bh Bs[2][64 * BK];  // 2 x 8 KB

    const int tid = threadIdx.x;
    const int w = tid >> 6, lane = tid & 63;
    const int l15 = lane & 15, l4 = lane >> 4;
    const int i = (int)blockIdx.x;
    const int xcd = i & 7, j = i >> 3;           // j 0..127
    const int bm = xcd * 16 + (j >> 3);          // 0..127
    const int bn = j & 7;                        // 0..7
    const int m0 = bm * 64, n0 = bn * 64;
    const int wr = w >> 1, wc = w & 1;           // wave tile 32x32

    f32x4 acc[2][2] = {};
    const int sr = lane >> 3;
    const int cbx = (lane & 7) ^ sr;

    auto stage = [&](int buf, int kk) {
        #pragma unroll
        for (int ii = 0; ii < 2; ++ii) {
            const int idx = w * 2 + ii;
            const int r = idx * 8 + sr;
            gload_lds16(A + (size_t)(m0 + r) * DD + kk + 8 * cbx, &As[buf][idx * 512]);
            gload_lds16(Bt + (size_t)(n0 + r) * DD + kk + 8 * cbx, &Bs[buf][idx * 512]);
        }
    };

    stage(0, 0);
    __syncthreads();

    for (int kt = 0; kt < NKT; ++kt) {
        const int buf = kt & 1;
        if (kt > 0) { WAITVM(0); __builtin_amdgcn_s_barrier(); }
        if (kt + 1 < NKT) stage(buf ^ 1, (kt + 1) * BK);

        const char* Ab = (const char*)&As[buf][0];
        const char* Bb = (const char*)&Bs[buf][0];
        #pragma unroll
        for (int ks = 0; ks < 2; ++ks) {
            bf16x8 af[2], bfr[2];
            const int cby = ks * 64 + l4 * 16;
            #pragma unroll
            for (int mf = 0; mf < 2; ++mf) {
                const int row = wr * 32 + mf * 16 + l15;
                af[mf] = *(const bf16x8*)(Ab + row * 128 + (cby ^ ((row & 7) << 4)));
            }
            #pragma unroll
            for (int nf = 0; nf < 2; ++nf) {
                const int row = wc * 32 + nf * 16 + l15;
                bfr[nf] = *(const bf16x8*)(Bb + row * 128 + (cby ^ ((row & 7) << 4)));
            }
            __builtin_amdgcn_s_setprio(1);
            #pragma unroll
            for (int mf = 0; mf < 2; ++mf)
                #pragma unroll
                for (int nf = 0; nf < 2; ++nf)
                    acc[mf][nf] = __builtin_amdgcn_mfma_f32_16x16x32_bf16(
                        af[mf], bfr[nf], acc[mf][nf], 0, 0, 0);
            __builtin_amdgcn_s_setprio(0);
        }
    }

    #pragma unroll
    for (int nf = 0; nf < 2; ++nf) {
        const int n = n0 + wc * 32 + nf * 16 + l15;
        const float bi = bias[n];
        float g = 0.f, be = 0.f, mu = 0.f, iv = 0.f;
        if constexpr (EP == 1) {
            g = gamma[n]; be = beta[n]; mu = mean[n];
            iv = rsqrtf(var[n] + BN_EPS);
        }
        #pragma unroll
        for (int mf = 0; mf < 2; ++mf) {
            #pragma unroll
            for (int r = 0; r < 4; ++r) {
                const int m = m0 + wr * 32 + mf * 16 + l4 * 4 + r;
                const size_t off = (size_t)m * DD + n;
                const float v = acc[mf][nf][r] + bi;
                if constexpr (EP == 2) {
                    outb[off] = (bh)fmaxf(v, 0.f);
                } else {
                    const float t = (float)resb[off] + v;
                    const float s = (t - mu) * iv * g + be;
                    outb[off] = (bh)s;
                    if constexpr (WF32) Xo[off] = s;
                }
            }
        }
    }
}

// ---------------- fused QKV GEMM; K/V written in MFMA-fragment-blocked layout ----------
// K_blk chunk = (bh*64 + tile)*4 + s          : elem(lane,j) = K[key=l&31][dk=s*16+(l>>5)*8+j]
// V_blk chunk = (bh*64 + tile)*4 + half*2 + ks: elem(lane,j) = V[dk=32*half+(l&31)][key=ks*16+(l>>5)*8+j]
__global__ __launch_bounds__(256, 3)
void gemm_qkv(const bh* __restrict__ A, const bh* __restrict__ Bt,
              const float* __restrict__ bq, const float* __restrict__ bk,
              const float* __restrict__ bv,
              bh* __restrict__ qb, bh* __restrict__ kblk, bh* __restrict__ vblk) {
    constexpr int BM = 128, BN = 64, BK = 64, NKT = DD / BK;
    __shared__ __align__(16) bh As[2][BM * BK];
    __shared__ __align__(16) bh Bs[2][BN * BK];

    const int tid = threadIdx.x;
    const int w = tid >> 6, lane = tid & 63;
    const int l15 = lane & 15, l4 = lane >> 4;
    const int i = (int)blockIdx.x;
    const int xcd = i & 7, j = i >> 3;        // j 0..191
    const int bm = xcd * 8 + (j & 7);         // 0..63
    const int bn = j >> 3;                    // 0..23
    const int m0 = bm * BM, n0 = bn * BN;
    const int wr = w >> 1, wc = w & 1;

    f32x4 acc[4][2] = {};
    const int sr = lane >> 3;
    const int cbx = (lane & 7) ^ sr;

    auto stage = [&](int buf, int kk) {
        #pragma unroll
        for (int ii = 0; ii < 4; ++ii) {
            const int idx = w * 4 + ii;
            const int r = idx * 8 + sr;
            gload_lds16(A + (size_t)(m0 + r) * DD + kk + 8 * cbx, &As[buf][idx * 512]);
        }
        #pragma unroll
        for (int ii = 0; ii < 2; ++ii) {
            const int idx = w * 2 + ii;
            const int r = idx * 8 + sr;
            gload_lds16(Bt + (size_t)(n0 + r) * DD + kk + 8 * cbx, &Bs[buf][idx * 512]);
        }
    };

    stage(0, 0);
    stage(1, BK);

    for (int kt = 0; kt < NKT; ++kt) {
        const int buf = kt & 1;
        if (kt + 1 < NKT) { WAITVM(6); } else { WAITVM(0); }
        __builtin_amdgcn_s_barrier();

        const char* Ab = (const char*)&As[buf][0];
        const char* Bb = (const char*)&Bs[buf][0];
        #pragma unroll
        for (int ks = 0; ks < 2; ++ks) {
            bf16x8 af[4], bfr[2];
            const int cby = ks * 64 + l4 * 16;
            #pragma unroll
            for (int mf = 0; mf < 4; ++mf) {
                const int row = wr * 64 + mf * 16 + l15;
                af[mf] = *(const bf16x8*)(Ab + row * 128 + (cby ^ ((row & 7) << 4)));
            }
            #pragma unroll
            for (int nf = 0; nf < 2; ++nf) {
                const int row = wc * 32 + nf * 16 + l15;
                bfr[nf] = *(const bf16x8*)(Bb + row * 128 + (cby ^ ((row & 7) << 4)));
            }
            #pragma unroll
            for (int mf = 0; mf < 4; ++mf)
                #pragma unroll
                for (int nf = 0; nf < 2; ++nf)
                    acc[mf][nf] = __builtin_amdgcn_mfma_f32_16x16x32_bf16(
                        af[mf], bfr[nf], acc[mf][nf], 0, 0, 0);
        }
        WAITLGKM0;
        __builtin_amdgcn_s_barrier();
        if (kt + 2 < NKT) stage(buf, (kt + 2) * BK);
    }

    const int part = n0 >> 9;                 // uniform per block: 0=Q 1=K 2=V
    #pragma unroll
    for (int nf = 0; nf < 2; ++nf) {
        const int n = n0 + wc * 32 + nf * 16 + l15;
        const int nn = n & 511;
        const float bi = (part == 0 ? bq : part == 1 ? bk : bv)[nn];
        if (part == 0) {
            #pragma unroll
            for (int mf = 0; mf < 4; ++mf)
                #pragma unroll
                for (int r = 0; r < 4; ++r) {
                    const int m = m0 + wr * 64 + mf * 16 + l4 * 4 + r;
                    qb[(size_t)m * DD + nn] = (bh)(acc[mf][nf][r] + bi);
                }
        } else if (part == 1) {
            const int hh = nn >> 6, dk = nn & 63;
            const int s = dk >> 4, hib = (dk >> 3) & 1, jj = dk & 7;
            #pragma unroll
            for (int mf = 0; mf < 4; ++mf)
                #pragma unroll
                for (int r = 0; r < 4; ++r) {
                    const int m = m0 + wr * 64 + mf * 16 + l4 * 4 + r;
                    const int b2 = m >> 11, sq = m & (SS - 1);
                    const int tile = sq >> 5, key5 = sq & 31;
                    kblk[(size_t)(((b2 * HH + hh) * 64 + tile) * 4 + s) * 512 +
                         (key5 + 32 * hib) * 8 + jj] = (bh)(acc[mf][nf][r] + bi);
                }
        } else {
            const int hh = nn >> 6, dk = nn & 63;
            const int half = dk >> 5, lanelow = dk & 31;
            #pragma unroll
            for (int mf = 0; mf < 4; ++mf) {
                const int m = m0 + wr * 64 + mf * 16 + l4 * 4;   // key base, mult of 4
                const int b2 = m >> 11, sq = m & (SS - 1);
                const int tile = sq >> 5, key5 = sq & 31;
                const int ks = key5 >> 4, hib = (key5 >> 3) & 1, jb = key5 & 7;
                union { bh h4[4]; uint64_t u; } pk;
                #pragma unroll
                for (int r = 0; r < 4; ++r)
                    pk.h4[r] = (bh)(acc[mf][nf][r] + bi);
                *(uint64_t*)(vblk + (size_t)(((b2 * HH + hh) * 64 + tile) * 4 +
                             half * 2 + ks) * 512 + (lanelow + 32 * hib) * 8 + jb) = pk.u;
            }
        }
    }
}

// ---------------- flash attention v7: 32x32 MFMA, zero LDS, zero barriers ----------------
// grid 1024 (XCD-pinned), 2 waves x 32q = 64 q/block. K/V fragments loaded from blocked
// global layout (L2-resident), 1-tile register prefetch (2 named generations, static).
// Swapped MFMA; P stays in registers via cvt_pk_bf16 + permlane32_swap (T12).
__global__ __launch_bounds__(128, 2)
void flash_attn(const bh* __restrict__ Q, const bh* __restrict__ Kb_,
                const bh* __restrict__ Vb_, const float* __restrict__ mb,
                bh* __restrict__ O) {
    constexpr int KVB = 32, NT = SS / KVB;       // 64 tiles
    constexpr float CSC = 0.18033688f;           // 0.125 * log2(e)

    const int tid = threadIdx.x;
    const int w = tid >> 6, lane = tid & 63;
    const int l31 = lane & 31, hi = lane >> 5;

    const int i = (int)blockIdx.x;
    const int xcd = i & 7, j = i >> 3;           // j 0..127
    const int g = xcd * 4 + (j >> 5);            // (b,h) group 0..31
    const int qt = j & 31;
    const int h = g & 7, b = g >> 3;
    const int q0 = qt * 64 + w * 32;

    // Q B-frags: qf[s]: Q[q = q0 + l31][dk = s*16 + hi*8 + j]
    const bh* qp = Q + (size_t)(b * SS + q0 + l31) * DD + h * 64 + hi * 8;
    const bf16x8 qf0 = *(const bf16x8*)(qp);
    const bf16x8 qf1 = *(const bf16x8*)(qp + 16);
    const bf16x8 qf2 = *(const bf16x8*)(qp + 32);
    const bf16x8 qf3 = *(const bf16x8*)(qp + 48);

    const bh* kbase = Kb_ + (size_t)((b * HH + h) * 256) * 512 + lane * 8;
    const bh* vbase = Vb_ + (size_t)((b * HH + h) * 256) * 512 + lane * 8;
    const float* mbb = mb + (size_t)b * SS + hi * 4;

    f32x16 ctx0 = {}, ctx1 = {};
    float accl = 0.f, m2 = -3e38f;

    bf16x8 kA0, kA1, kA2, kA3, vA0, vA1, vA2, vA3;
    bf16x8 kB0, kB1, kB2, kB3, vB0, vB1, vB2, vB3;
    f32x4 mA0, mA1, mA2, mA3, mB0, mB1, mB2, mB3;

#define PREF(G, t) do {                                                   \
        const bh* kp_ = kbase + (size_t)(t) * 2048;                       \
        k##G##0 = *(const bf16x8*)(kp_);                                  \
        k##G##1 = *(const bf16x8*)(kp_ + 512);                            \
        k##G##2 = *(const bf16x8*)(kp_ + 1024);                           \
        k##G##3 = *(const bf16x8*)(kp_ + 1536);                           \
        const bh* vp_ = vbase + (size_t)(t) * 2048;                       \
        v##G##0 = *(const bf16x8*)(vp_);                                  \
        v##G##1 = *(const bf16x8*)(vp_ + 512);                            \
        v##G##2 = *(const bf16x8*)(vp_ + 1024);                           \
        v##G##3 = *(const bf16x8*)(vp_ + 1536);                           \
        const float* mp_ = mbb + (t) * KVB;                               \
        m##G##0 = *(const f32x4*)(mp_);                                   \
        m##G##1 = *(const f32x4*)(mp_ + 8);                               \
        m##G##2 = *(const f32x4*)(mp_ + 16);                              \
        m##G##3 = *(const f32x4*)(mp_ + 24);                              \
    } while (0)

    auto compute = [&](const bf16x8& K0, const bf16x8& K1, const bf16x8& K2, const bf16x8& K3,
                       const bf16x8& V0, const bf16x8& V1, const bf16x8& V2, const bf16x8& V3,
                       const f32x4& M0, const f32x4& M1, const f32x4& M2, const f32x4& M3) {
        // QK^T (swapped): sc = D[key][q=l31], key = kt + (r&3)+8*(r>>2)+4*hi
        f32x16 sc = {};
        __builtin_amdgcn_s_setprio(1);
        sc = __builtin_amdgcn_mfma_f32_32x32x16_bf16(K0, qf0, sc, 0, 0, 0);
        sc = __builtin_amdgcn_mfma_f32_32x32x16_bf16(K1, qf1, sc, 0, 0, 0);
        sc = __builtin_amdgcn_mfma_f32_32x32x16_bf16(K2, qf2, sc, 0, 0, 0);
        sc = __builtin_amdgcn_mfma_f32_32x32x16_bf16(K3, qf3, sc, 0, 0, 0);
        __builtin_amdgcn_s_setprio(0);

        const f32x4 mm[4] = {M0, M1, M2, M3};
        float z[16];
        float tm = -3e38f;
        #pragma unroll
        for (int qg = 0; qg < 4; ++qg)
            #pragma unroll
            for (int c = 0; c < 4; ++c) {
                const float zz = fmaf(sc[qg * 4 + c], CSC, mm[qg][c]);
                z[qg * 4 + c] = zz;
                tm = fmaxf(tm, zz);
            }
        if (__any(tm > m2 + 11.5f)) {            // rare after warm-up
            const float tp = fmaxf(tm, __shfl_xor(tm, 32, 64));
            const float mn = fmaxf(fmaxf(tp, m2), -60.f);
            const float fac = __builtin_amdgcn_exp2f(m2 - mn);
            m2 = mn;
            accl *= fac;
            #pragma unroll
            for (int r = 0; r < 16; ++r) { ctx0[r] *= fac; ctx1[r] *= fac; }
        }
        uint32_t pk[8];
        float ps = 0.f;
        #pragma unroll
        for (int i2 = 0; i2 < 8; ++i2) {
            const float p0 = __builtin_amdgcn_exp2f(z[2 * i2] - m2);
            const float p1 = __builtin_amdgcn_exp2f(z[2 * i2 + 1] - m2);
            ps += p0 + p1;
            asm("v_cvt_pk_bf16_f32 %0, %1, %2" : "=v"(pk[i2]) : "v"(p0), "v"(p1));
        }
        accl += ps;
        // halves exchange: after in-place swaps, pk[0..3] / pk[4..7] are PV B-frags ks=0 / ks=1
        asm("v_permlane32_swap_b32 %0, %1" : "+v"(pk[0]), "+v"(pk[2]));
        asm("v_permlane32_swap_b32 %0, %1" : "+v"(pk[1]), "+v"(pk[3]));
        asm("v_permlane32_swap_b32 %0, %1" : "+v"(pk[4]), "+v"(pk[6]));
        asm("v_permlane32_swap_b32 %0, %1" : "+v"(pk[5]), "+v"(pk[7]));
        union U { uint32_t d[4]; bf16x8 v; } u0, u1;
        u0.d[0] = pk[0]; u0.d[1] = pk[1]; u0.d[2] = pk[2]; u0.d[3] = pk[3];
        u1.d[0] = pk[4]; u1.d[1] = pk[5]; u1.d[2] = pk[6]; u1.d[3] = pk[7];
        __builtin_amdgcn_s_setprio(1);
        ctx0 = __builtin_amdgcn_mfma_f32_32x32x16_bf16(V0, u0.v, ctx0, 0, 0, 0);
        ctx0 = __builtin_amdgcn_mfma_f32_32x32x16_bf16(V1, u1.v, ctx0, 0, 0, 0);
        ctx1 = __builtin_amdgcn_mfma_f32_32x32x16_bf16(V2, u0.v, ctx1, 0, 0, 0);
        ctx1 = __builtin_amdgcn_mfma_f32_32x32x16_bf16(V3, u1.v, ctx1, 0, 0, 0);
        __builtin_amdgcn_s_setprio(0);
    };

    PREF(A, 0);
    for (int t = 0; t < NT; t += 2) {
        PREF(B, t + 1);
        compute(kA0, kA1, kA2, kA3, vA0, vA1, vA2, vA3, mA0, mA1, mA2, mA3);
        PREF(A, t + 2);   // tile NT reads into guard region (never used)
        compute(kB0, kB1, kB2, kB3, vB0, vB1, vB2, vB3, mB0, mB1, mB2, mB3);
    }
#undef PREF

    // epilogue: q = q0 + l31; dk = (r&3) + 8*(r>>2) + 4*hi + 32*half
    const float lr = accl + __shfl_xor(accl, 32, 64);
    const float linv = 1.0f / lr;
    bh* op = O + (size_t)(b * SS + q0 + l31) * DD + h * 64 + hi * 4;
    #pragma unroll
    for (int rg = 0; rg < 4; ++rg) {
        union { bh h4[4]; uint64_t u; } pk0, pk1;
        #pragma unroll
        for (int r = 0; r < 4; ++r) {
            pk0.h4[r] = (bh)(ctx0[rg * 4 + r] * linv);
            pk1.h4[r] = (bh)(ctx1[rg * 4 + r] * linv);
        }
        *(uint64_t*)(op + rg * 8) = pk0.u;
        *(uint64_t*)(op + 32 + rg * 8) = pk1.u;
    }
}

// ---------------- host launch ----------------
extern "C" void kernel_launch(void* const* d_in, const int* in_sizes, int n_in,
                              void* d_out, int out_size, void* d_ws, size_t ws_size,
                              hipStream_t stream) {
    const int*   seq  = (const int*)  d_in[0];
    const float* mask = (const float*)d_in[1];
    const float* pos  = (const float*)d_in[2];
    const float* emb  = (const float*)d_in[3];
    const float* wq = (const float*)d_in[4];  const float* bq = (const float*)d_in[5];
    const float* wk = (const float*)d_in[6];  const float* bk = (const float*)d_in[7];
    const float* wv = (const float*)d_in[8];  const float* bv = (const float*)d_in[9];
    const float* wo = (const float*)d_in[10]; const float* bo = (const float*)d_in[11];
    const float* ag = (const float*)d_in[12]; const float* ab = (const float*)d_in[13];
    const float* am = (const float*)d_in[14]; const float* av = (const float*)d_in[15];
    const float* d1w = (const float*)d_in[16]; const float* d1b = (const float*)d_in[17];
    const float* d2w = (const float*)d_in[18]; const float* d2b = (const float*)d_in[19];
    const float* fg = (const float*)d_in[20]; const float* fb = (const float*)d_in[21];
    const float* fm = (const float*)d_in[22]; const float* fv = (const float*)d_in[23];

    float* X = (float*)d_out;

    char* p = (char*)d_ws;
    auto take = [&](size_t n) { char* q = p; p += (n + 255) & ~(size_t)255; return q; };
    const size_t WE  = (size_t)LL * DD * DD;
    const size_t WQE = (size_t)LL * 3 * DD * DD;
    bh* wcat = (bh*)take(WQE * 2);
    bh* wot = (bh*)take(WE * 2);
    bh* w1t = (bh*)take(WE * 2);
    bh* w2t = (bh*)take(WE * 2);
    const size_t AE = (size_t)NTOK * DD;
    bh* xb   = (bh*)take(AE * 2);
    bh* qb   = (bh*)take(AE * 2);
    bh* kblk = (bh*)take(AE * 2);
    bh* vblk = (bh*)take(AE * 2);
    bh* ctxb = (bh*)take(AE * 2);
    bh* subb = (bh*)take(AE * 2);
    bh* h1b  = (bh*)take(AE * 2);
    float* mbias = (float*)take((size_t)BB * SS * 4);
    (void)take(16384);   // guard region for flash's harmless tail prefetch

    const int QKV_OS = 3 * DD * DD;
    wprep_all<<<dim3(16, 16, 24), dim3(32, 8), 0, stream>>>(
        wq, wk, wv, wo, d1w, d2w, wcat, wot, w1t, w2t);

    maskprep<<<dim3(BB * SS / 1024), dim3(256), 0, stream>>>(mask, mbias);
    embed_k<<<dim3(NTOK), dim3(128), 0, stream>>>(seq, emb, pos, xb);

    for (int l = 0; l < LL; ++l) {
        const size_t wof = (size_t)l * DD * DD;
        const int    bof = l * DD;
        gemm_qkv<<<dim3(1536), dim3(256), 0, stream>>>(
            xb, wcat + (size_t)l * QKV_OS, bq + bof, bk + bof, bv + bof, qb, kblk, vblk);
        flash_attn<<<dim3(1024), dim3(128), 0, stream>>>(qb, kblk, vblk, mbias, ctxb);
        gemm64<1, false><<<dim3(1024), dim3(256), 0, stream>>>(
            ctxb, wot + wof, bo + bof, subb, xb, nullptr,
            ag + bof, ab + bof, am + bof, av + bof);
        gemm64<2, false><<<dim3(1024), dim3(256), 0, stream>>>(
            subb, w1t + wof, d1b + bof, h1b, nullptr, nullptr,
            nullptr, nullptr, nullptr, nullptr);
        if (l + 1 < LL) {
            gemm64<1, false><<<dim3(1024), dim3(256), 0, stream>>>(
                h1b, w2t + wof, d2b + bof, xb, subb, nullptr,
                fg + bof, fb + bof, fm + bof, fv + bof);
        } else {
            gemm64<1, true><<<dim3(1024), dim3(256), 0, stream>>>(
                h1b, w2t + wof, d2b + bof, xb, subb, X,
                fg + bof, fb + bof, fm + bof, fv + bof);
        }
    }
}

// Round 10
// 432.294 us; speedup vs baseline: 1.3992x; 1.0007x over previous
//
#include <hip/hip_runtime.h>
#include <stdint.h>
#include <stddef.h>

// ---------------- problem constants ----------------
constexpr int BB = 4, SS = 2048, DD = 512, HH = 8, LL = 4;
constexpr int NTOK = BB * SS;          // 8192 tokens
constexpr float BN_EPS = 1e-3f;

using bh = __bf16;
typedef __bf16 bf16x8 __attribute__((ext_vector_type(8)));
typedef float  f32x4  __attribute__((ext_vector_type(4)));
typedef float  f32x16 __attribute__((ext_vector_type(16)));

#define DEV __device__ __forceinline__
#define WAITVM(n) asm volatile("s_waitcnt vmcnt(" #n ")" ::: "memory")
#define WAITLGKM0 asm volatile("s_waitcnt lgkmcnt(0)" ::: "memory")

DEV void gload_lds16(const void* g, void* l) {
    __builtin_amdgcn_global_load_lds(
        (const __attribute__((address_space(1))) void*)g,
        (__attribute__((address_space(3))) void*)l, 16, 0, 0);
}

// ---------------- weight prep (all 6 matrices, one dispatch) ----------------
__global__ void wprep_all(const float* __restrict__ wq, const float* __restrict__ wk,
                          const float* __restrict__ wv, const float* __restrict__ wo,
                          const float* __restrict__ d1, const float* __restrict__ d2,
                          bh* __restrict__ wcat, bh* __restrict__ wot,
                          bh* __restrict__ w1t, bh* __restrict__ w2t) {
    __shared__ float t[32][33];
    const int z = blockIdx.z;              // 0..23
    const int m = z >> 2, l = z & 3;
    constexpr int QOS = 3 * DD * DD;
    const float* src;
    bh* dst;
    switch (m) {
        case 0:  src = wq; dst = wcat + (size_t)l * QOS;               break;
        case 1:  src = wk; dst = wcat + (size_t)l * QOS + DD * DD;     break;
        case 2:  src = wv; dst = wcat + (size_t)l * QOS + 2 * DD * DD; break;
        case 3:  src = wo; dst = wot + (size_t)l * DD * DD;            break;
        case 4:  src = d1; dst = w1t + (size_t)l * DD * DD;            break;
        default: src = d2; dst = w2t + (size_t)l * DD * DD;            break;
    }
    src += (size_t)l * DD * DD;
    const int r0 = blockIdx.y * 32, c0 = blockIdx.x * 32;
    const int tx = threadIdx.x, ty = threadIdx.y;   // 32 x 8
    #pragma unroll
    for (int i = ty; i < 32; i += 8) t[i][tx] = src[(size_t)(r0 + i) * DD + c0 + tx];
    __syncthreads();
    #pragma unroll
    for (int i = ty; i < 32; i += 8) dst[(size_t)(c0 + i) * DD + r0 + tx] = (bh)t[tx][i];
}

// ---------------- mask bias: [B,S] f32 -> 0 / -1e30 ----------------
__global__ void maskprep(const float* __restrict__ mask, float* __restrict__ mb) {
    const int i = ((int)blockIdx.x * 256 + threadIdx.x) * 4;
    const float4 m4 = *(const float4*)(mask + i);
    float4 o;
    o.x = (m4.x == 0.f) ? -1e30f : 0.f;
    o.y = (m4.y == 0.f) ? -1e30f : 0.f;
    o.z = (m4.z == 0.f) ? -1e30f : 0.f;
    o.w = (m4.w == 0.f) ? -1e30f : 0.f;
    *(float4*)(mb + i) = o;
}

// ---------------- embedding + positional -> bf16 ----------------
__global__ void embed_k(const int* __restrict__ seq, const float* __restrict__ emb,
                        const float* __restrict__ pos, bh* __restrict__ xb) {
    const int m = blockIdx.x;                // 0..8191
    const int s = m & (SS - 1);
    const int tok = seq[m];
    const int d = threadIdx.x * 4;           // 128 threads * 4 floats
    const float4 e  = *(const float4*)(emb + (size_t)tok * DD + d);
    const float4 pz = *(const float4*)(pos + (size_t)s * DD + d);
    union { bh h[4]; uint64_t u; } pk;
    pk.h[0] = (bh)(e.x + pz.x); pk.h[1] = (bh)(e.y + pz.y);
    pk.h[2] = (bh)(e.z + pz.z); pk.h[3] = (bh)(e.w + pz.w);
    *(uint64_t*)(xb + (size_t)m * DD + d) = pk.u;
}

// ---------------- GEMM 64x64 tile (round-5 proven version) ----------------
// EP 1: t = resb + acc + bias; s = BN(t); outb = bf16(s); if WF32: Xo = s
// EP 2: outb = bf16(relu(acc + bias))
template <int EP, bool WF32>
__global__ __launch_bounds__(256, 4)
void gemm64(const bh* __restrict__ A, const bh* __restrict__ Bt,
            const float* __restrict__ bias, bh* __restrict__ outb,
            const bh* __restrict__ resb, float* __restrict__ Xo,
            const float* __restrict__ gamma, const float* __restrict__ beta,
            const float* __restrict__ mean, const float* __restrict__ var) {
    constexpr int BK = 64, NKT = DD / BK;        // 8 k-tiles
    __shared__ __align__(16) bh As[2][64 * BK];  // 2 x 8 KB
    __shared__ __align__(16) bh Bs[2][64 * BK];  // 2 x 8 KB

    const int tid = threadIdx.x;
    const int w = tid >> 6, lane = tid & 63;
    const int l15 = lane & 15, l4 = lane >> 4;
    const int i = (int)blockIdx.x;
    const int xcd = i & 7, j = i >> 3;           // j 0..127
    const int bm = xcd * 16 + (j >> 3);          // 0..127
    const int bn = j & 7;                        // 0..7
    const int m0 = bm * 64, n0 = bn * 64;
    const int wr = w >> 1, wc = w & 1;           // wave tile 32x32

    f32x4 acc[2][2] = {};
    const int sr = lane >> 3;
    const int cbx = (lane & 7) ^ sr;

    auto stage = [&](int buf, int kk) {
        #pragma unroll
        for (int ii = 0; ii < 2; ++ii) {
            const int idx = w * 2 + ii;
            const int r = idx * 8 + sr;
            gload_lds16(A + (size_t)(m0 + r) * DD + kk + 8 * cbx, &As[buf][idx * 512]);
            gload_lds16(Bt + (size_t)(n0 + r) * DD + kk + 8 * cbx, &Bs[buf][idx * 512]);
        }
    };

    stage(0, 0);
    __syncthreads();

    for (int kt = 0; kt < NKT; ++kt) {
        const int buf = kt & 1;
        if (kt > 0) { WAITVM(0); __builtin_amdgcn_s_barrier(); }
        if (kt + 1 < NKT) stage(buf ^ 1, (kt + 1) * BK);

        const char* Ab = (const char*)&As[buf][0];
        const char* Bb = (const char*)&Bs[buf][0];
        #pragma unroll
        for (int ks = 0; ks < 2; ++ks) {
            bf16x8 af[2], bfr[2];
            const int cby = ks * 64 + l4 * 16;
            #pragma unroll
            for (int mf = 0; mf < 2; ++mf) {
                const int row = wr * 32 + mf * 16 + l15;
                af[mf] = *(const bf16x8*)(Ab + row * 128 + (cby ^ ((row & 7) << 4)));
            }
            #pragma unroll
            for (int nf = 0; nf < 2; ++nf) {
                const int row = wc * 32 + nf * 16 + l15;
                bfr[nf] = *(const bf16x8*)(Bb + row * 128 + (cby ^ ((row & 7) << 4)));
            }
            __builtin_amdgcn_s_setprio(1);
            #pragma unroll
            for (int mf = 0; mf < 2; ++mf)
                #pragma unroll
                for (int nf = 0; nf < 2; ++nf)
                    acc[mf][nf] = __builtin_amdgcn_mfma_f32_16x16x32_bf16(
                        af[mf], bfr[nf], acc[mf][nf], 0, 0, 0);
            __builtin_amdgcn_s_setprio(0);
        }
    }

    #pragma unroll
    for (int nf = 0; nf < 2; ++nf) {
        const int n = n0 + wc * 32 + nf * 16 + l15;
        const float bi = bias[n];
        float g = 0.f, be = 0.f, mu = 0.f, iv = 0.f;
        if constexpr (EP == 1) {
            g = gamma[n]; be = beta[n]; mu = mean[n];
            iv = rsqrtf(var[n] + BN_EPS);
        }
        #pragma unroll
        for (int mf = 0; mf < 2; ++mf) {
            #pragma unroll
            for (int r = 0; r < 4; ++r) {
                const int m = m0 + wr * 32 + mf * 16 + l4 * 4 + r;
                const size_t off = (size_t)m * DD + n;
                const float v = acc[mf][nf][r] + bi;
                if constexpr (EP == 2) {
                    outb[off] = (bh)fmaxf(v, 0.f);
                } else {
                    const float t = (float)resb[off] + v;
                    const float s = (t - mu) * iv * g + be;
                    outb[off] = (bh)s;
                    if constexpr (WF32) Xo[off] = s;
                }
            }
        }
    }
}

// ---------------- fused QKV GEMM; K/V written in MFMA-fragment-blocked layout ----------
// K_blk chunk = (bh*64 + tile)*4 + s          : elem(lane,j) = K[key=l&31][dk=s*16+(l>>5)*8+j]
// V_blk chunk = (bh*64 + tile)*4 + half*2 + ks: elem(lane,j) = V[dk=32*half+(l&31)][key=ks*16+(l>>5)*8+j]
__global__ __launch_bounds__(256, 3)
void gemm_qkv(const bh* __restrict__ A, const bh* __restrict__ Bt,
              const float* __restrict__ bq, const float* __restrict__ bk,
              const float* __restrict__ bv,
              bh* __restrict__ qb, bh* __restrict__ kblk, bh* __restrict__ vblk) {
    constexpr int BM = 128, BN = 64, BK = 64, NKT = DD / BK;
    __shared__ __align__(16) bh As[2][BM * BK];
    __shared__ __align__(16) bh Bs[2][BN * BK];

    const int tid = threadIdx.x;
    const int w = tid >> 6, lane = tid & 63;
    const int l15 = lane & 15, l4 = lane >> 4;
    const int i = (int)blockIdx.x;
    const int xcd = i & 7, j = i >> 3;        // j 0..191
    const int bm = xcd * 8 + (j & 7);         // 0..63
    const int bn = j >> 3;                    // 0..23
    const int m0 = bm * BM, n0 = bn * BN;
    const int wr = w >> 1, wc = w & 1;

    f32x4 acc[4][2] = {};
    const int sr = lane >> 3;
    const int cbx = (lane & 7) ^ sr;

    auto stage = [&](int buf, int kk) {
        #pragma unroll
        for (int ii = 0; ii < 4; ++ii) {
            const int idx = w * 4 + ii;
            const int r = idx * 8 + sr;
            gload_lds16(A + (size_t)(m0 + r) * DD + kk + 8 * cbx, &As[buf][idx * 512]);
        }
        #pragma unroll
        for (int ii = 0; ii < 2; ++ii) {
            const int idx = w * 2 + ii;
            const int r = idx * 8 + sr;
            gload_lds16(Bt + (size_t)(n0 + r) * DD + kk + 8 * cbx, &Bs[buf][idx * 512]);
        }
    };

    stage(0, 0);
    stage(1, BK);

    for (int kt = 0; kt < NKT; ++kt) {
        const int buf = kt & 1;
        if (kt + 1 < NKT) { WAITVM(6); } else { WAITVM(0); }
        __builtin_amdgcn_s_barrier();

        const char* Ab = (const char*)&As[buf][0];
        const char* Bb = (const char*)&Bs[buf][0];
        #pragma unroll
        for (int ks = 0; ks < 2; ++ks) {
            bf16x8 af[4], bfr[2];
            const int cby = ks * 64 + l4 * 16;
            #pragma unroll
            for (int mf = 0; mf < 4; ++mf) {
                const int row = wr * 64 + mf * 16 + l15;
                af[mf] = *(const bf16x8*)(Ab + row * 128 + (cby ^ ((row & 7) << 4)));
            }
            #pragma unroll
            for (int nf = 0; nf < 2; ++nf) {
                const int row = wc * 32 + nf * 16 + l15;
                bfr[nf] = *(const bf16x8*)(Bb + row * 128 + (cby ^ ((row & 7) << 4)));
            }
            #pragma unroll
            for (int mf = 0; mf < 4; ++mf)
                #pragma unroll
                for (int nf = 0; nf < 2; ++nf)
                    acc[mf][nf] = __builtin_amdgcn_mfma_f32_16x16x32_bf16(
                        af[mf], bfr[nf], acc[mf][nf], 0, 0, 0);
        }
        WAITLGKM0;
        __builtin_amdgcn_s_barrier();
        if (kt + 2 < NKT) stage(buf, (kt + 2) * BK);
    }

    const int part = n0 >> 9;                 // uniform per block: 0=Q 1=K 2=V
    #pragma unroll
    for (int nf = 0; nf < 2; ++nf) {
        const int n = n0 + wc * 32 + nf * 16 + l15;
        const int nn = n & 511;
        const float bi = (part == 0 ? bq : part == 1 ? bk : bv)[nn];
        if (part == 0) {
            #pragma unroll
            for (int mf = 0; mf < 4; ++mf)
                #pragma unroll
                for (int r = 0; r < 4; ++r) {
                    const int m = m0 + wr * 64 + mf * 16 + l4 * 4 + r;
                    qb[(size_t)m * DD + nn] = (bh)(acc[mf][nf][r] + bi);
                }
        } else if (part == 1) {
            const int hh = nn >> 6, dk = nn & 63;
            const int s = dk >> 4, hib = (dk >> 3) & 1, jj = dk & 7;
            #pragma unroll
            for (int mf = 0; mf < 4; ++mf)
                #pragma unroll
                for (int r = 0; r < 4; ++r) {
                    const int m = m0 + wr * 64 + mf * 16 + l4 * 4 + r;
                    const int b2 = m >> 11, sq = m & (SS - 1);
                    const int tile = sq >> 5, key5 = sq & 31;
                    kblk[(size_t)(((b2 * HH + hh) * 64 + tile) * 4 + s) * 512 +
                         (key5 + 32 * hib) * 8 + jj] = (bh)(acc[mf][nf][r] + bi);
                }
        } else {
            const int hh = nn >> 6, dk = nn & 63;
            const int half = dk >> 5, lanelow = dk & 31;
            #pragma unroll
            for (int mf = 0; mf < 4; ++mf) {
                const int m = m0 + wr * 64 + mf * 16 + l4 * 4;   // key base, mult of 4
                const int b2 = m >> 11, sq = m & (SS - 1);
                const int tile = sq >> 5, key5 = sq & 31;
                const int ks = key5 >> 4, hib = (key5 >> 3) & 1, jb = key5 & 7;
                union { bh h4[4]; uint64_t u; } pk;
                #pragma unroll
                for (int r = 0; r < 4; ++r)
                    pk.h4[r] = (bh)(acc[mf][nf][r] + bi);
                *(uint64_t*)(vblk + (size_t)(((b2 * HH + hh) * 64 + tile) * 4 +
                             half * 2 + ks) * 512 + (lanelow + 32 * hib) * 8 + jb) = pk.u;
            }
        }
    }
}

// ---------------- flash attention v7: 32x32 MFMA, zero LDS, zero barriers ----------------
// grid 1024 (XCD-pinned), 2 waves x 32q = 64 q/block. K/V fragments loaded from blocked
// global layout (L2-resident), 1-tile register prefetch (2 named generations, static).
// Swapped MFMA; P stays in registers via cvt_pk_bf16 + permlane32_swap (T12).
__global__ __launch_bounds__(128, 2)
void flash_attn(const bh* __restrict__ Q, const bh* __restrict__ Kb_,
                const bh* __restrict__ Vb_, const float* __restrict__ mb,
                bh* __restrict__ O) {
    constexpr int KVB = 32, NT = SS / KVB;       // 64 tiles
    constexpr float CSC = 0.18033688f;           // 0.125 * log2(e)

    const int tid = threadIdx.x;
    const int w = tid >> 6, lane = tid & 63;
    const int l31 = lane & 31, hi = lane >> 5;

    const int i = (int)blockIdx.x;
    const int xcd = i & 7, j = i >> 3;           // j 0..127
    const int g = xcd * 4 + (j >> 5);            // (b,h) group 0..31
    const int qt = j & 31;
    const int h = g & 7, b = g >> 3;
    const int q0 = qt * 64 + w * 32;

    // Q B-frags: qf[s]: Q[q = q0 + l31][dk = s*16 + hi*8 + j]
    const bh* qp = Q + (size_t)(b * SS + q0 + l31) * DD + h * 64 + hi * 8;
    const bf16x8 qf0 = *(const bf16x8*)(qp);
    const bf16x8 qf1 = *(const bf16x8*)(qp + 16);
    const bf16x8 qf2 = *(const bf16x8*)(qp + 32);
    const bf16x8 qf3 = *(const bf16x8*)(qp + 48);

    const bh* kbase = Kb_ + (size_t)((b * HH + h) * 256) * 512 + lane * 8;
    const bh* vbase = Vb_ + (size_t)((b * HH + h) * 256) * 512 + lane * 8;
    const float* mbb = mb + (size_t)b * SS + hi * 4;

    f32x16 ctx0 = {}, ctx1 = {};
    float accl = 0.f, m2 = -3e38f;

    bf16x8 kA0, kA1, kA2, kA3, vA0, vA1, vA2, vA3;
    bf16x8 kB0, kB1, kB2, kB3, vB0, vB1, vB2, vB3;
    f32x4 mA0, mA1, mA2, mA3, mB0, mB1, mB2, mB3;

#define PREF(G, t) do {                                                   \
        const bh* kp_ = kbase + (size_t)(t) * 2048;                       \
        k##G##0 = *(const bf16x8*)(kp_);                                  \
        k##G##1 = *(const bf16x8*)(kp_ + 512);                            \
        k##G##2 = *(const bf16x8*)(kp_ + 1024);                           \
        k##G##3 = *(const bf16x8*)(kp_ + 1536);                           \
        const bh* vp_ = vbase + (size_t)(t) * 2048;                       \
        v##G##0 = *(const bf16x8*)(vp_);                                  \
        v##G##1 = *(const bf16x8*)(vp_ + 512);                            \
        v##G##2 = *(const bf16x8*)(vp_ + 1024);                           \
        v##G##3 = *(const bf16x8*)(vp_ + 1536);                           \
        const float* mp_ = mbb + (t) * KVB;                               \
        m##G##0 = *(const f32x4*)(mp_);                                   \
        m##G##1 = *(const f32x4*)(mp_ + 8);                               \
        m##G##2 = *(const f32x4*)(mp_ + 16);                              \
        m##G##3 = *(const f32x4*)(mp_ + 24);                              \
    } while (0)

    auto compute = [&](const bf16x8& K0, const bf16x8& K1, const bf16x8& K2, const bf16x8& K3,
                       const bf16x8& V0, const bf16x8& V1, const bf16x8& V2, const bf16x8& V3,
                       const f32x4& M0, const f32x4& M1, const f32x4& M2, const f32x4& M3) {
        // QK^T (swapped): sc = D[key][q=l31], key = kt + (r&3)+8*(r>>2)+4*hi
        f32x16 sc = {};
        __builtin_amdgcn_s_setprio(1);
        sc = __builtin_amdgcn_mfma_f32_32x32x16_bf16(K0, qf0, sc, 0, 0, 0);
        sc = __builtin_amdgcn_mfma_f32_32x32x16_bf16(K1, qf1, sc, 0, 0, 0);
        sc = __builtin_amdgcn_mfma_f32_32x32x16_bf16(K2, qf2, sc, 0, 0, 0);
        sc = __builtin_amdgcn_mfma_f32_32x32x16_bf16(K3, qf3, sc, 0, 0, 0);
        __builtin_amdgcn_s_setprio(0);

        const f32x4 mm[4] = {M0, M1, M2, M3};
        float z[16];
        float tm = -3e38f;
        #pragma unroll
        for (int qg = 0; qg < 4; ++qg)
            #pragma unroll
            for (int c = 0; c < 4; ++c) {
                const float zz = fmaf(sc[qg * 4 + c], CSC, mm[qg][c]);
                z[qg * 4 + c] = zz;
                tm = fmaxf(tm, zz);
            }
        if (__any(tm > m2 + 11.5f)) {            // rare after warm-up
            const float tp = fmaxf(tm, __shfl_xor(tm, 32, 64));
            const float mn = fmaxf(fmaxf(tp, m2), -60.f);
            const float fac = __builtin_amdgcn_exp2f(m2 - mn);
            m2 = mn;
            accl *= fac;
            #pragma unroll
            for (int r = 0; r < 16; ++r) { ctx0[r] *= fac; ctx1[r] *= fac; }
        }
        uint32_t pk[8];
        float ps = 0.f;
        #pragma unroll
        for (int i2 = 0; i2 < 8; ++i2) {
            const float p0 = __builtin_amdgcn_exp2f(z[2 * i2] - m2);
            const float p1 = __builtin_amdgcn_exp2f(z[2 * i2 + 1] - m2);
            ps += p0 + p1;
            asm("v_cvt_pk_bf16_f32 %0, %1, %2" : "=v"(pk[i2]) : "v"(p0), "v"(p1));
        }
        accl += ps;
        // halves exchange: after in-place swaps, pk[0..3] / pk[4..7] are PV B-frags ks=0 / ks=1
        asm("v_permlane32_swap_b32 %0, %1" : "+v"(pk[0]), "+v"(pk[2]));
        asm("v_permlane32_swap_b32 %0, %1" : "+v"(pk[1]), "+v"(pk[3]));
        asm("v_permlane32_swap_b32 %0, %1" : "+v"(pk[4]), "+v"(pk[6]));
        asm("v_permlane32_swap_b32 %0, %1" : "+v"(pk[5]), "+v"(pk[7]));
        union U { uint32_t d[4]; bf16x8 v; } u0, u1;
        u0.d[0] = pk[0]; u0.d[1] = pk[1]; u0.d[2] = pk[2]; u0.d[3] = pk[3];
        u1.d[0] = pk[4]; u1.d[1] = pk[5]; u1.d[2] = pk[6]; u1.d[3] = pk[7];
        __builtin_amdgcn_s_setprio(1);
        ctx0 = __builtin_amdgcn_mfma_f32_32x32x16_bf16(V0, u0.v, ctx0, 0, 0, 0);
        ctx0 = __builtin_amdgcn_mfma_f32_32x32x16_bf16(V1, u1.v, ctx0, 0, 0, 0);
        ctx1 = __builtin_amdgcn_mfma_f32_32x32x16_bf16(V2, u0.v, ctx1, 0, 0, 0);
        ctx1 = __builtin_amdgcn_mfma_f32_32x32x16_bf16(V3, u1.v, ctx1, 0, 0, 0);
        __builtin_amdgcn_s_setprio(0);
    };

    PREF(A, 0);
    for (int t = 0; t < NT; t += 2) {
        PREF(B, t + 1);
        compute(kA0, kA1, kA2, kA3, vA0, vA1, vA2, vA3, mA0, mA1, mA2, mA3);
        PREF(A, t + 2);   // tile NT reads into guard region (never used)
        compute(kB0, kB1, kB2, kB3, vB0, vB1, vB2, vB3, mB0, mB1, mB2, mB3);
    }
#undef PREF

    // epilogue: q = q0 + l31; dk = (r&3) + 8*(r>>2) + 4*hi + 32*half
    const float lr = accl + __shfl_xor(accl, 32, 64);
    const float linv = 1.0f / lr;
    bh* op = O + (size_t)(b * SS + q0 + l31) * DD + h * 64 + hi * 4;
    #pragma unroll
    for (int rg = 0; rg < 4; ++rg) {
        union { bh h4[4]; uint64_t u; } pk0, pk1;
        #pragma unroll
        for (int r = 0; r < 4; ++r) {
            pk0.h4[r] = (bh)(ctx0[rg * 4 + r] * linv);
            pk1.h4[r] = (bh)(ctx1[rg * 4 + r] * linv);
        }
        *(uint64_t*)(op + rg * 8) = pk0.u;
        *(uint64_t*)(op + 32 + rg * 8) = pk1.u;
    }
}

// ---------------- host launch ----------------
extern "C" void kernel_launch(void* const* d_in, const int* in_sizes, int n_in,
                              void* d_out, int out_size, void* d_ws, size_t ws_size,
                              hipStream_t stream) {
    const int*   seq  = (const int*)  d_in[0];
    const float* mask = (const float*)d_in[1];
    const float* pos  = (const float*)d_in[2];
    const float* emb  = (const float*)d_in[3];
    const float* wq = (const float*)d_in[4];  const float* bq = (const float*)d_in[5];
    const float* wk = (const float*)d_in[6];  const float* bk = (const float*)d_in[7];
    const float* wv = (const float*)d_in[8];  const float* bv = (const float*)d_in[9];
    const float* wo = (const float*)d_in[10]; const float* bo = (const float*)d_in[11];
    const float* ag = (const float*)d_in[12]; const float* ab = (const float*)d_in[13];
    const float* am = (const float*)d_in[14]; const float* av = (const float*)d_in[15];
    const float* d1w = (const float*)d_in[16]; const float* d1b = (const float*)d_in[17];
    const float* d2w = (const float*)d_in[18]; const float* d2b = (const float*)d_in[19];
    const float* fg = (const float*)d_in[20]; const float* fb = (const float*)d_in[21];
    const float* fm = (const float*)d_in[22]; const float* fv = (const float*)d_in[23];

    float* X = (float*)d_out;

    char* p = (char*)d_ws;
    auto take = [&](size_t n) { char* q = p; p += (n + 255) & ~(size_t)255; return q; };
    const size_t WE  = (size_t)LL * DD * DD;
    const size_t WQE = (size_t)LL * 3 * DD * DD;
    bh* wcat = (bh*)take(WQE * 2);
    bh* wot = (bh*)take(WE * 2);
    bh* w1t = (bh*)take(WE * 2);
    bh* w2t = (bh*)take(WE * 2);
    const size_t AE = (size_t)NTOK * DD;
    bh* xb   = (bh*)take(AE * 2);
    bh* qb   = (bh*)take(AE * 2);
    bh* kblk = (bh*)take(AE * 2);
    bh* vblk = (bh*)take(AE * 2);
    bh* ctxb = (bh*)take(AE * 2);
    bh* subb = (bh*)take(AE * 2);
    bh* h1b  = (bh*)take(AE * 2);
    float* mbias = (float*)take((size_t)BB * SS * 4);
    (void)take(16384);   // guard region for flash's harmless tail prefetch

    const int QKV_OS = 3 * DD * DD;
    wprep_all<<<dim3(16, 16, 24), dim3(32, 8), 0, stream>>>(
        wq, wk, wv, wo, d1w, d2w, wcat, wot, w1t, w2t);

    maskprep<<<dim3(BB * SS / 1024), dim3(256), 0, stream>>>(mask, mbias);
    embed_k<<<dim3(NTOK), dim3(128), 0, stream>>>(seq, emb, pos, xb);

    for (int l = 0; l < LL; ++l) {
        const size_t wof = (size_t)l * DD * DD;
        const int    bof = l * DD;
        gemm_qkv<<<dim3(1536), dim3(256), 0, stream>>>(
            xb, wcat + (size_t)l * QKV_OS, bq + bof, bk + bof, bv + bof, qb, kblk, vblk);
        flash_attn<<<dim3(1024), dim3(128), 0, stream>>>(qb, kblk, vblk, mbias, ctxb);
        gemm64<1, false><<<dim3(1024), dim3(256), 0, stream>>>(
            ctxb, wot + wof, bo + bof, subb, xb, nullptr,
            ag + bof, ab + bof, am + bof, av + bof);
        gemm64<2, false><<<dim3(1024), dim3(256), 0, stream>>>(
            subb, w1t + wof, d1b + bof, h1b, nullptr, nullptr,
            nullptr, nullptr, nullptr, nullptr);
        if (l + 1 < LL) {
            gemm64<1, false><<<dim3(1024), dim3(256), 0, stream>>>(
                h1b, w2t + wof, d2b + bof, xb, subb, nullptr,
                fg + bof, fb + bof, fm + bof, fv + bof);
        } else {
            gemm64<1, true><<<dim3(1024), dim3(256), 0, stream>>>(
                h1b, w2t + wof, d2b + bof, xb, subb, X,
                fg + bof, fb + bof, fm + bof, fv + bof);
        }
    }
}

// Round 11
// 431.944 us; speedup vs baseline: 1.4004x; 1.0008x over previous
//
#include <hip/hip_runtime.h>
#include <stdint.h>
#include <stddef.h>

// ---------------- problem constants ----------------
constexpr int BB = 4, SS = 2048, DD = 512, HH = 8, LL = 4;
constexpr int NTOK = BB * SS;          // 8192 tokens
constexpr float BN_EPS = 1e-3f;

using bh = __bf16;
typedef __bf16 bf16x8 __attribute__((ext_vector_type(8)));
typedef float  f32x4  __attribute__((ext_vector_type(4)));
typedef float  f32x16 __attribute__((ext_vector_type(16)));

#define DEV __device__ __forceinline__
#define WAITVM(n) asm volatile("s_waitcnt vmcnt(" #n ")" ::: "memory")
#define WAITLGKM0 asm volatile("s_waitcnt lgkmcnt(0)" ::: "memory")

DEV void gload_lds16(const void* g, void* l) {
    __builtin_amdgcn_global_load_lds(
        (const __attribute__((address_space(1))) void*)g,
        (__attribute__((address_space(3))) void*)l, 16, 0, 0);
}

// ---------------- weight prep (all 6 matrices, one dispatch) ----------------
__global__ void wprep_all(const float* __restrict__ wq, const float* __restrict__ wk,
                          const float* __restrict__ wv, const float* __restrict__ wo,
                          const float* __restrict__ d1, const float* __restrict__ d2,
                          bh* __restrict__ wcat, bh* __restrict__ wot,
                          bh* __restrict__ w1t, bh* __restrict__ w2t) {
    __shared__ float t[32][33];
    const int z = blockIdx.z;              // 0..23
    const int m = z >> 2, l = z & 3;
    constexpr int QOS = 3 * DD * DD;
    const float* src;
    bh* dst;
    switch (m) {
        case 0:  src = wq; dst = wcat + (size_t)l * QOS;               break;
        case 1:  src = wk; dst = wcat + (size_t)l * QOS + DD * DD;     break;
        case 2:  src = wv; dst = wcat + (size_t)l * QOS + 2 * DD * DD; break;
        case 3:  src = wo; dst = wot + (size_t)l * DD * DD;            break;
        case 4:  src = d1; dst = w1t + (size_t)l * DD * DD;            break;
        default: src = d2; dst = w2t + (size_t)l * DD * DD;            break;
    }
    src += (size_t)l * DD * DD;
    const int r0 = blockIdx.y * 32, c0 = blockIdx.x * 32;
    const int tx = threadIdx.x, ty = threadIdx.y;   // 32 x 8
    #pragma unroll
    for (int i = ty; i < 32; i += 8) t[i][tx] = src[(size_t)(r0 + i) * DD + c0 + tx];
    __syncthreads();
    #pragma unroll
    for (int i = ty; i < 32; i += 8) dst[(size_t)(c0 + i) * DD + r0 + tx] = (bh)t[tx][i];
}

// ---------------- mask bias: [B,S] f32 -> 0 / -1e30 ----------------
__global__ void maskprep(const float* __restrict__ mask, float* __restrict__ mb) {
    const int i = ((int)blockIdx.x * 256 + threadIdx.x) * 4;
    const float4 m4 = *(const float4*)(mask + i);
    float4 o;
    o.x = (m4.x == 0.f) ? -1e30f : 0.f;
    o.y = (m4.y == 0.f) ? -1e30f : 0.f;
    o.z = (m4.z == 0.f) ? -1e30f : 0.f;
    o.w = (m4.w == 0.f) ? -1e30f : 0.f;
    *(float4*)(mb + i) = o;
}

// ---------------- embedding + positional -> bf16 ----------------
__global__ void embed_k(const int* __restrict__ seq, const float* __restrict__ emb,
                        const float* __restrict__ pos, bh* __restrict__ xb) {
    const int m = blockIdx.x;                // 0..8191
    const int s = m & (SS - 1);
    const int tok = seq[m];
    const int d = threadIdx.x * 4;           // 128 threads * 4 floats
    const float4 e  = *(const float4*)(emb + (size_t)tok * DD + d);
    const float4 pz = *(const float4*)(pos + (size_t)s * DD + d);
    union { bh h[4]; uint64_t u; } pk;
    pk.h[0] = (bh)(e.x + pz.x); pk.h[1] = (bh)(e.y + pz.y);
    pk.h[2] = (bh)(e.z + pz.z); pk.h[3] = (bh)(e.w + pz.w);
    *(uint64_t*)(xb + (size_t)m * DD + d) = pk.u;
}

// ---------------- GEMM 64x64 tile (round-5 proven version) ----------------
// EP 1: t = resb + acc + bias; s = BN(t); outb = bf16(s); if WF32: Xo = s
// EP 2: outb = bf16(relu(acc + bias))
template <int EP, bool WF32>
__global__ __launch_bounds__(256, 4)
void gemm64(const bh* __restrict__ A, const bh* __restrict__ Bt,
            const float* __restrict__ bias, bh* __restrict__ outb,
            const bh* __restrict__ resb, float* __restrict__ Xo,
            const float* __restrict__ gamma, const float* __restrict__ beta,
            const float* __restrict__ mean, const float* __restrict__ var) {
    constexpr int BK = 64, NKT = DD / BK;        // 8 k-tiles
    __shared__ __align__(16) bh As[2][64 * BK];  // 2 x 8 KB
    __shared__ __align__(16) bh Bs[2][64 * BK];  // 2 x 8 KB

    const int tid = threadIdx.x;
    const int w = tid >> 6, lane = tid & 63;
    const int l15 = lane & 15, l4 = lane >> 4;
    const int i = (int)blockIdx.x;
    const int xcd = i & 7, j = i >> 3;           // j 0..127
    const int bm = xcd * 16 + (j >> 3);          // 0..127
    const int bn = j & 7;                        // 0..7
    const int m0 = bm * 64, n0 = bn * 64;
    const int wr = w >> 1, wc = w & 1;           // wave tile 32x32

    f32x4 acc[2][2] = {};
    const int sr = lane >> 3;
    const int cbx = (lane & 7) ^ sr;

    auto stage = [&](int buf, int kk) {
        #pragma unroll
        for (int ii = 0; ii < 2; ++ii) {
            const int idx = w * 2 + ii;
            const int r = idx * 8 + sr;
            gload_lds16(A + (size_t)(m0 + r) * DD + kk + 8 * cbx, &As[buf][idx * 512]);
            gload_lds16(Bt + (size_t)(n0 + r) * DD + kk + 8 * cbx, &Bs[buf][idx * 512]);
        }
    };

    stage(0, 0);
    __syncthreads();

    for (int kt = 0; kt < NKT; ++kt) {
        const int buf = kt & 1;
        if (kt > 0) { WAITVM(0); __builtin_amdgcn_s_barrier(); }
        if (kt + 1 < NKT) stage(buf ^ 1, (kt + 1) * BK);

        const char* Ab = (const char*)&As[buf][0];
        const char* Bb = (const char*)&Bs[buf][0];
        #pragma unroll
        for (int ks = 0; ks < 2; ++ks) {
            bf16x8 af[2], bfr[2];
            const int cby = ks * 64 + l4 * 16;
            #pragma unroll
            for (int mf = 0; mf < 2; ++mf) {
                const int row = wr * 32 + mf * 16 + l15;
                af[mf] = *(const bf16x8*)(Ab + row * 128 + (cby ^ ((row & 7) << 4)));
            }
            #pragma unroll
            for (int nf = 0; nf < 2; ++nf) {
                const int row = wc * 32 + nf * 16 + l15;
                bfr[nf] = *(const bf16x8*)(Bb + row * 128 + (cby ^ ((row & 7) << 4)));
            }
            __builtin_amdgcn_s_setprio(1);
            #pragma unroll
            for (int mf = 0; mf < 2; ++mf)
                #pragma unroll
                for (int nf = 0; nf < 2; ++nf)
                    acc[mf][nf] = __builtin_amdgcn_mfma_f32_16x16x32_bf16(
                        af[mf], bfr[nf], acc[mf][nf], 0, 0, 0);
            __builtin_amdgcn_s_setprio(0);
        }
    }

    #pragma unroll
    for (int nf = 0; nf < 2; ++nf) {
        const int n = n0 + wc * 32 + nf * 16 + l15;
        const float bi = bias[n];
        float g = 0.f, be = 0.f, mu = 0.f, iv = 0.f;
        if constexpr (EP == 1) {
            g = gamma[n]; be = beta[n]; mu = mean[n];
            iv = rsqrtf(var[n] + BN_EPS);
        }
        #pragma unroll
        for (int mf = 0; mf < 2; ++mf) {
            #pragma unroll
            for (int r = 0; r < 4; ++r) {
                const int m = m0 + wr * 32 + mf * 16 + l4 * 4 + r;
                const size_t off = (size_t)m * DD + n;
                const float v = acc[mf][nf][r] + bi;
                if constexpr (EP == 2) {
                    outb[off] = (bh)fmaxf(v, 0.f);
                } else {
                    const float t = (float)resb[off] + v;
                    const float s = (t - mu) * iv * g + be;
                    outb[off] = (bh)s;
                    if constexpr (WF32) Xo[off] = s;
                }
            }
        }
    }
}

// ---------------- fused QKV GEMM; K/V written in MFMA-fragment-blocked layout ----------
// K_blk chunk = (bh*64 + tile)*4 + s          : elem(lane,j) = K[key=l&31][dk=s*16+(l>>5)*8+j]
// V_blk chunk = (bh*64 + tile)*4 + half*2 + ks: elem(lane,j) = V[dk=32*half+(l&31)][key=ks*16+(l>>5)*8+j]
__global__ __launch_bounds__(256, 3)
void gemm_qkv(const bh* __restrict__ A, const bh* __restrict__ Bt,
              const float* __restrict__ bq, const float* __restrict__ bk,
              const float* __restrict__ bv,
              bh* __restrict__ qb, bh* __restrict__ kblk, bh* __restrict__ vblk) {
    constexpr int BM = 128, BN = 64, BK = 64, NKT = DD / BK;
    __shared__ __align__(16) bh As[2][BM * BK];
    __shared__ __align__(16) bh Bs[2][BN * BK];

    const int tid = threadIdx.x;
    const int w = tid >> 6, lane = tid & 63;
    const int l15 = lane & 15, l4 = lane >> 4;
    const int i = (int)blockIdx.x;
    const int xcd = i & 7, j = i >> 3;        // j 0..191
    const int bm = xcd * 8 + (j & 7);         // 0..63
    const int bn = j >> 3;                    // 0..23
    const int m0 = bm * BM, n0 = bn * BN;
    const int wr = w >> 1, wc = w & 1;

    f32x4 acc[4][2] = {};
    const int sr = lane >> 3;
    const int cbx = (lane & 7) ^ sr;

    auto stage = [&](int buf, int kk) {
        #pragma unroll
        for (int ii = 0; ii < 4; ++ii) {
            const int idx = w * 4 + ii;
            const int r = idx * 8 + sr;
            gload_lds16(A + (size_t)(m0 + r) * DD + kk + 8 * cbx, &As[buf][idx * 512]);
        }
        #pragma unroll
        for (int ii = 0; ii < 2; ++ii) {
            const int idx = w * 2 + ii;
            const int r = idx * 8 + sr;
            gload_lds16(Bt + (size_t)(n0 + r) * DD + kk + 8 * cbx, &Bs[buf][idx * 512]);
        }
    };

    stage(0, 0);
    stage(1, BK);

    for (int kt = 0; kt < NKT; ++kt) {
        const int buf = kt & 1;
        if (kt + 1 < NKT) { WAITVM(6); } else { WAITVM(0); }
        __builtin_amdgcn_s_barrier();

        const char* Ab = (const char*)&As[buf][0];
        const char* Bb = (const char*)&Bs[buf][0];
        #pragma unroll
        for (int ks = 0; ks < 2; ++ks) {
            bf16x8 af[4], bfr[2];
            const int cby = ks * 64 + l4 * 16;
            #pragma unroll
            for (int mf = 0; mf < 4; ++mf) {
                const int row = wr * 64 + mf * 16 + l15;
                af[mf] = *(const bf16x8*)(Ab + row * 128 + (cby ^ ((row & 7) << 4)));
            }
            #pragma unroll
            for (int nf = 0; nf < 2; ++nf) {
                const int row = wc * 32 + nf * 16 + l15;
                bfr[nf] = *(const bf16x8*)(Bb + row * 128 + (cby ^ ((row & 7) << 4)));
            }
            #pragma unroll
            for (int mf = 0; mf < 4; ++mf)
                #pragma unroll
                for (int nf = 0; nf < 2; ++nf)
                    acc[mf][nf] = __builtin_amdgcn_mfma_f32_16x16x32_bf16(
                        af[mf], bfr[nf], acc[mf][nf], 0, 0, 0);
        }
        WAITLGKM0;
        __builtin_amdgcn_s_barrier();
        if (kt + 2 < NKT) stage(buf, (kt + 2) * BK);
    }

    const int part = n0 >> 9;                 // uniform per block: 0=Q 1=K 2=V
    #pragma unroll
    for (int nf = 0; nf < 2; ++nf) {
        const int n = n0 + wc * 32 + nf * 16 + l15;
        const int nn = n & 511;
        const float bi = (part == 0 ? bq : part == 1 ? bk : bv)[nn];
        if (part == 0) {
            #pragma unroll
            for (int mf = 0; mf < 4; ++mf)
                #pragma unroll
                for (int r = 0; r < 4; ++r) {
                    const int m = m0 + wr * 64 + mf * 16 + l4 * 4 + r;
                    qb[(size_t)m * DD + nn] = (bh)(acc[mf][nf][r] + bi);
                }
        } else if (part == 1) {
            const int hh = nn >> 6, dk = nn & 63;
            const int s = dk >> 4, hib = (dk >> 3) & 1, jj = dk & 7;
            #pragma unroll
            for (int mf = 0; mf < 4; ++mf)
                #pragma unroll
                for (int r = 0; r < 4; ++r) {
                    const int m = m0 + wr * 64 + mf * 16 + l4 * 4 + r;
                    const int b2 = m >> 11, sq = m & (SS - 1);
                    const int tile = sq >> 5, key5 = sq & 31;
                    kblk[(size_t)(((b2 * HH + hh) * 64 + tile) * 4 + s) * 512 +
                         (key5 + 32 * hib) * 8 + jj] = (bh)(acc[mf][nf][r] + bi);
                }
        } else {
            const int hh = nn >> 6, dk = nn & 63;
            const int half = dk >> 5, lanelow = dk & 31;
            #pragma unroll
            for (int mf = 0; mf < 4; ++mf) {
                const int m = m0 + wr * 64 + mf * 16 + l4 * 4;   // key base, mult of 4
                const int b2 = m >> 11, sq = m & (SS - 1);
                const int tile = sq >> 5, key5 = sq & 31;
                const int ks = key5 >> 4, hib = (key5 >> 3) & 1, jb = key5 & 7;
                union { bh h4[4]; uint64_t u; } pk;
                #pragma unroll
                for (int r = 0; r < 4; ++r)
                    pk.h4[r] = (bh)(acc[mf][nf][r] + bi);
                *(uint64_t*)(vblk + (size_t)(((b2 * HH + hh) * 64 + tile) * 4 +
                             half * 2 + ks) * 512 + (lanelow + 32 * hib) * 8 + jb) = pk.u;
            }
        }
    }
}

// ---------------- flash attention v7: 32x32 MFMA, zero LDS, zero barriers ----------------
// grid 1024 (XCD-pinned), 2 waves x 32q = 64 q/block. K/V fragments loaded from blocked
// global layout (L2-resident), 1-tile register prefetch (2 named generations, static).
// Swapped MFMA; P stays in registers via cvt_pk_bf16 + permlane32_swap (T12).
__global__ __launch_bounds__(128, 2)
void flash_attn(const bh* __restrict__ Q, const bh* __restrict__ Kb_,
                const bh* __restrict__ Vb_, const float* __restrict__ mb,
                bh* __restrict__ O) {
    constexpr int KVB = 32, NT = SS / KVB;       // 64 tiles
    constexpr float CSC = 0.18033688f;           // 0.125 * log2(e)

    const int tid = threadIdx.x;
    const int w = tid >> 6, lane = tid & 63;
    const int l31 = lane & 31, hi = lane >> 5;

    const int i = (int)blockIdx.x;
    const int xcd = i & 7, j = i >> 3;           // j 0..127
    const int g = xcd * 4 + (j >> 5);            // (b,h) group 0..31
    const int qt = j & 31;
    const int h = g & 7, b = g >> 3;
    const int q0 = qt * 64 + w * 32;

    // Q B-frags: qf[s]: Q[q = q0 + l31][dk = s*16 + hi*8 + j]
    const bh* qp = Q + (size_t)(b * SS + q0 + l31) * DD + h * 64 + hi * 8;
    const bf16x8 qf0 = *(const bf16x8*)(qp);
    const bf16x8 qf1 = *(const bf16x8*)(qp + 16);
    const bf16x8 qf2 = *(const bf16x8*)(qp + 32);
    const bf16x8 qf3 = *(const bf16x8*)(qp + 48);

    const bh* kbase = Kb_ + (size_t)((b * HH + h) * 256) * 512 + lane * 8;
    const bh* vbase = Vb_ + (size_t)((b * HH + h) * 256) * 512 + lane * 8;
    const float* mbb = mb + (size_t)b * SS + hi * 4;

    f32x16 ctx0 = {}, ctx1 = {};
    float accl = 0.f, m2 = -3e38f;

    bf16x8 kA0, kA1, kA2, kA3, vA0, vA1, vA2, vA3;
    bf16x8 kB0, kB1, kB2, kB3, vB0, vB1, vB2, vB3;
    f32x4 mA0, mA1, mA2, mA3, mB0, mB1, mB2, mB3;

#define PREF(G, t) do {                                                   \
        const bh* kp_ = kbase + (size_t)(t) * 2048;                       \
        k##G##0 = *(const bf16x8*)(kp_);                                  \
        k##G##1 = *(const bf16x8*)(kp_ + 512);                            \
        k##G##2 = *(const bf16x8*)(kp_ + 1024);                           \
        k##G##3 = *(const bf16x8*)(kp_ + 1536);                           \
        const bh* vp_ = vbase + (size_t)(t) * 2048;                       \
        v##G##0 = *(const bf16x8*)(vp_);                                  \
        v##G##1 = *(const bf16x8*)(vp_ + 512);                            \
        v##G##2 = *(const bf16x8*)(vp_ + 1024);                           \
        v##G##3 = *(const bf16x8*)(vp_ + 1536);                           \
        const float* mp_ = mbb + (t) * KVB;                               \
        m##G##0 = *(const f32x4*)(mp_);                                   \
        m##G##1 = *(const f32x4*)(mp_ + 8);                               \
        m##G##2 = *(const f32x4*)(mp_ + 16);                              \
        m##G##3 = *(const f32x4*)(mp_ + 24);                              \
    } while (0)

    auto compute = [&](const bf16x8& K0, const bf16x8& K1, const bf16x8& K2, const bf16x8& K3,
                       const bf16x8& V0, const bf16x8& V1, const bf16x8& V2, const bf16x8& V3,
                       const f32x4& M0, const f32x4& M1, const f32x4& M2, const f32x4& M3) {
        // QK^T (swapped): sc = D[key][q=l31], key = kt + (r&3)+8*(r>>2)+4*hi
        f32x16 sc = {};
        __builtin_amdgcn_s_setprio(1);
        sc = __builtin_amdgcn_mfma_f32_32x32x16_bf16(K0, qf0, sc, 0, 0, 0);
        sc = __builtin_amdgcn_mfma_f32_32x32x16_bf16(K1, qf1, sc, 0, 0, 0);
        sc = __builtin_amdgcn_mfma_f32_32x32x16_bf16(K2, qf2, sc, 0, 0, 0);
        sc = __builtin_amdgcn_mfma_f32_32x32x16_bf16(K3, qf3, sc, 0, 0, 0);
        __builtin_amdgcn_s_setprio(0);

        const f32x4 mm[4] = {M0, M1, M2, M3};
        float z[16];
        float tm = -3e38f;
        #pragma unroll
        for (int qg = 0; qg < 4; ++qg)
            #pragma unroll
            for (int c = 0; c < 4; ++c) {
                const float zz = fmaf(sc[qg * 4 + c], CSC, mm[qg][c]);
                z[qg * 4 + c] = zz;
                tm = fmaxf(tm, zz);
            }
        if (__any(tm > m2 + 11.5f)) {            // rare after warm-up
            const float tp = fmaxf(tm, __shfl_xor(tm, 32, 64));
            const float mn = fmaxf(fmaxf(tp, m2), -60.f);
            const float fac = __builtin_amdgcn_exp2f(m2 - mn);
            m2 = mn;
            accl *= fac;
            #pragma unroll
            for (int r = 0; r < 16; ++r) { ctx0[r] *= fac; ctx1[r] *= fac; }
        }
        uint32_t pk[8];
        float ps = 0.f;
        #pragma unroll
        for (int i2 = 0; i2 < 8; ++i2) {
            const float p0 = __builtin_amdgcn_exp2f(z[2 * i2] - m2);
            const float p1 = __builtin_amdgcn_exp2f(z[2 * i2 + 1] - m2);
            ps += p0 + p1;
            asm("v_cvt_pk_bf16_f32 %0, %1, %2" : "=v"(pk[i2]) : "v"(p0), "v"(p1));
        }
        accl += ps;
        // halves exchange: after in-place swaps, pk[0..3] / pk[4..7] are PV B-frags ks=0 / ks=1
        asm("v_permlane32_swap_b32 %0, %1" : "+v"(pk[0]), "+v"(pk[2]));
        asm("v_permlane32_swap_b32 %0, %1" : "+v"(pk[1]), "+v"(pk[3]));
        asm("v_permlane32_swap_b32 %0, %1" : "+v"(pk[4]), "+v"(pk[6]));
        asm("v_permlane32_swap_b32 %0, %1" : "+v"(pk[5]), "+v"(pk[7]));
        union U { uint32_t d[4]; bf16x8 v; } u0, u1;
        u0.d[0] = pk[0]; u0.d[1] = pk[1]; u0.d[2] = pk[2]; u0.d[3] = pk[3];
        u1.d[0] = pk[4]; u1.d[1] = pk[5]; u1.d[2] = pk[6]; u1.d[3] = pk[7];
        __builtin_amdgcn_s_setprio(1);
        ctx0 = __builtin_amdgcn_mfma_f32_32x32x16_bf16(V0, u0.v, ctx0, 0, 0, 0);
        ctx0 = __builtin_amdgcn_mfma_f32_32x32x16_bf16(V1, u1.v, ctx0, 0, 0, 0);
        ctx1 = __builtin_amdgcn_mfma_f32_32x32x16_bf16(V2, u0.v, ctx1, 0, 0, 0);
        ctx1 = __builtin_amdgcn_mfma_f32_32x32x16_bf16(V3, u1.v, ctx1, 0, 0, 0);
        __builtin_amdgcn_s_setprio(0);
    };

    PREF(A, 0);
    for (int t = 0; t < NT; t += 2) {
        PREF(B, t + 1);
        compute(kA0, kA1, kA2, kA3, vA0, vA1, vA2, vA3, mA0, mA1, mA2, mA3);
        PREF(A, t + 2);   // tile NT reads into guard region (never used)
        compute(kB0, kB1, kB2, kB3, vB0, vB1, vB2, vB3, mB0, mB1, mB2, mB3);
    }
#undef PREF

    // epilogue: q = q0 + l31; dk = (r&3) + 8*(r>>2) + 4*hi + 32*half
    const float lr = accl + __shfl_xor(accl, 32, 64);
    const float linv = 1.0f / lr;
    bh* op = O + (size_t)(b * SS + q0 + l31) * DD + h * 64 + hi * 4;
    #pragma unroll
    for (int rg = 0; rg < 4; ++rg) {
        union { bh h4[4]; uint64_t u; } pk0, pk1;
        #pragma unroll
        for (int r = 0; r < 4; ++r) {
            pk0.h4[r] = (bh)(ctx0[rg * 4 + r] * linv);
            pk1.h4[r] = (bh)(ctx1[rg * 4 + r] * linv);
        }
        *(uint64_t*)(op + rg * 8) = pk0.u;
        *(uint64_t*)(op + 32 + rg * 8) = pk1.u;
    }
}

// ---------------- host launch ----------------
extern "C" void kernel_launch(void* const* d_in, const int* in_sizes, int n_in,
                              void* d_out, int out_size, void* d_ws, size_t ws_size,
                              hipStream_t stream) {
    const int*   seq  = (const int*)  d_in[0];
    const float* mask = (const float*)d_in[1];
    const float* pos  = (const float*)d_in[2];
    const float* emb  = (const float*)d_in[3];
    const float* wq = (const float*)d_in[4];  const float* bq = (const float*)d_in[5];
    const float* wk = (const float*)d_in[6];  const float* bk = (const float*)d_in[7];
    const float* wv = (const float*)d_in[8];  const float* bv = (const float*)d_in[9];
    const float* wo = (const float*)d_in[10]; const float* bo = (const float*)d_in[11];
    const float* ag = (const float*)d_in[12]; const float* ab = (const float*)d_in[13];
    const float* am = (const float*)d_in[14]; const float* av = (const float*)d_in[15];
    const float* d1w = (const float*)d_in[16]; const float* d1b = (const float*)d_in[17];
    const float* d2w = (const float*)d_in[18]; const float* d2b = (const float*)d_in[19];
    const float* fg = (const float*)d_in[20]; const float* fb = (const float*)d_in[21];
    const float* fm = (const float*)d_in[22]; const float* fv = (const float*)d_in[23];

    float* X = (float*)d_out;

    char* p = (char*)d_ws;
    auto take = [&](size_t n) { char* q = p; p += (n + 255) & ~(size_t)255; return q; };
    const size_t WE  = (size_t)LL * DD * DD;
    const size_t WQE = (size_t)LL * 3 * DD * DD;
    bh* wcat = (bh*)take(WQE * 2);
    bh* wot = (bh*)take(WE * 2);
    bh* w1t = (bh*)take(WE * 2);
    bh* w2t = (bh*)take(WE * 2);
    const size_t AE = (size_t)NTOK * DD;
    bh* xb   = (bh*)take(AE * 2);
    bh* qb   = (bh*)take(AE * 2);
    bh* kblk = (bh*)take(AE * 2);
    bh* vblk = (bh*)take(AE * 2);
    bh* ctxb = (bh*)take(AE * 2);
    bh* subb = (bh*)take(AE * 2);
    bh* h1b  = (bh*)take(AE * 2);
    float* mbias = (float*)take((size_t)BB * SS * 4);
    (void)take(16384);   // guard region for flash's harmless tail prefetch

    const int QKV_OS = 3 * DD * DD;
    wprep_all<<<dim3(16, 16, 24), dim3(32, 8), 0, stream>>>(
        wq, wk, wv, wo, d1w, d2w, wcat, wot, w1t, w2t);

    maskprep<<<dim3(BB * SS / 1024), dim3(256), 0, stream>>>(mask, mbias);
    embed_k<<<dim3(NTOK), dim3(128), 0, stream>>>(seq, emb, pos, xb);

    for (int l = 0; l < LL; ++l) {
        const size_t wof = (size_t)l * DD * DD;
        const int    bof = l * DD;
        gemm_qkv<<<dim3(1536), dim3(256), 0, stream>>>(
            xb, wcat + (size_t)l * QKV_OS, bq + bof, bk + bof, bv + bof, qb, kblk, vblk);
        flash_attn<<<dim3(1024), dim3(128), 0, stream>>>(qb, kblk, vblk, mbias, ctxb);
        gemm64<1, false><<<dim3(1024), dim3(256), 0, stream>>>(
            ctxb, wot + wof, bo + bof, subb, xb, nullptr,
            ag + bof, ab + bof, am + bof, av + bof);
        gemm64<2, false><<<dim3(1024), dim3(256), 0, stream>>>(
            subb, w1t + wof, d1b + bof, h1b, nullptr, nullptr,
            nullptr, nullptr, nullptr, nullptr);
        if (l + 1 < LL) {
            gemm64<1, false><<<dim3(1024), dim3(256), 0, stream>>>(
                h1b, w2t + wof, d2b + bof, xb, subb, nullptr,
                fg + bof, fb + bof, fm + bof, fv + bof);
        } else {
            gemm64<1, true><<<dim3(1024), dim3(256), 0, stream>>>(
                h1b, w2t + wof, d2b + bof, xb, subb, X,
                fg + bof, fb + bof, fm + bof, fv + bof);
        }
    }
}